// Round 1
// baseline (171.507 us; speedup 1.0000x reference)
//
#include <hip/hip_runtime.h>
#include <hip/hip_bf16.h>

typedef __attribute__((ext_vector_type(8))) short bf16x8;
typedef __attribute__((ext_vector_type(4))) float f32x4;
typedef __attribute__((ext_vector_type(4))) unsigned int u32x4;

#define B_SZ 4
#define C_SZ 256
#define N_SZ 4096
#define DK_SZ 32

// ws layout in bf16 elements
#define WQB_OFF 0
#define WKB_OFF 8192
#define WVB_OFF 16384
#define QB_OFF  81920
#define KB_OFF  606208
#define VB_OFF  1130496

__device__ __forceinline__ short f2bf(float f) {
    union { float f; unsigned int u; } v; v.f = f;
    unsigned int r = v.u + 0x7fffu + ((v.u >> 16) & 1u);
    return (short)(r >> 16);
}
__device__ __forceinline__ float bf2f(short s) {
    union { float f; unsigned int u; } v;
    v.u = ((unsigned int)(unsigned short)s) << 16;
    return v.f;
}

__device__ __forceinline__ f32x4 mfma16(bf16x8 a, bf16x8 b, f32x4 c) {
    return __builtin_amdgcn_mfma_f32_16x16x32_bf16(a, b, c, 0, 0, 0);
}

// ---------------- weight conversion ----------------
__global__ __launch_bounds__(256) void k_convw(const float* __restrict__ Wq,
                                               const float* __restrict__ Wk,
                                               const float* __restrict__ Wv,
                                               short* __restrict__ ws) {
    int i = blockIdx.x * 256 + threadIdx.x;   // grid = 256 blocks -> i in [0, 65536)
    if (i < 8192) {
        ws[WQB_OFF + i] = f2bf(Wq[i]);
        ws[WKB_OFF + i] = f2bf(Wk[i]);
    }
    ws[WVB_OFF + i] = f2bf(Wv[i]);
}

// ---------------- projection: q, k as [b][n][32] bf16; v as [b][c][n] bf16 ----------------
__global__ __launch_bounds__(256) void k_prep(const float* __restrict__ x,
                                              const float* __restrict__ bq,
                                              const float* __restrict__ bk,
                                              const float* __restrict__ bv,
                                              short* __restrict__ ws) {
    __shared__ short xsT[64][264];   // x^T tile [n][c], padded
    __shared__ short vt_s[64][258];  // v^T tile [n][c] staging for transposed write

    const int b = blockIdx.y;
    const int n0 = blockIdx.x * 64;
    const int t = threadIdx.x;
    const float* xb = x + (size_t)b * C_SZ * N_SZ;

    // stage x tile, transposing to [n][c] bf16
    {
        int c0 = t >> 4, n4 = (t & 15) * 4;
#pragma unroll
        for (int i = 0; i < 16; i++) {
            int c = c0 + 16 * i;
            float4 v = *(const float4*)(xb + (size_t)c * N_SZ + n0 + n4);
            xsT[n4 + 0][c] = f2bf(v.x);
            xsT[n4 + 1][c] = f2bf(v.y);
            xsT[n4 + 2][c] = f2bf(v.z);
            xsT[n4 + 3][c] = f2bf(v.w);
        }
    }
    __syncthreads();

    const int w = t >> 6, l = t & 63;
    const int lr = l & 15, lk = l >> 4;

    // A fragments: rows = this wave's 16 n-rows, 8 contiguous c per lane
    bf16x8 af[8];
#pragma unroll
    for (int kk = 0; kk < 8; kk++)
        af[kk] = *(const bf16x8*)(&xsT[w * 16 + lr][kk * 32 + lk * 8]);

    // Q and K projections: out[n][d], d = 0..31 (2 col-fragments)
#pragma unroll
    for (int qk = 0; qk < 2; qk++) {
        const short* wb = ws + (qk ? WKB_OFF : WQB_OFF);
        const float* bias = qk ? bk : bq;
        short* outp = ws + (qk ? KB_OFF : QB_OFF) + (size_t)b * N_SZ * DK_SZ;
#pragma unroll
        for (int cf = 0; cf < 2; cf++) {
            f32x4 acc = {0.f, 0.f, 0.f, 0.f};
#pragma unroll
            for (int kk = 0; kk < 8; kk++) {
                bf16x8 bfr = *(const bf16x8*)(wb + (cf * 16 + lr) * 256 + kk * 32 + lk * 8);
                acc = mfma16(af[kk], bfr, acc);
            }
            float bias_v = bias[cf * 16 + lr];
#pragma unroll
            for (int r = 0; r < 4; r++) {
                int row = w * 16 + lk * 4 + r;
                outp[(size_t)(n0 + row) * DK_SZ + cf * 16 + lr] = f2bf(acc[r] + bias_v);
            }
        }
    }

    // V projection: v^T[n][c] into LDS, then transposed write to vb[c][n]
#pragma unroll
    for (int cf = 0; cf < 16; cf++) {
        f32x4 acc = {0.f, 0.f, 0.f, 0.f};
#pragma unroll
        for (int kk = 0; kk < 8; kk++) {
            bf16x8 bfr = *(const bf16x8*)(ws + WVB_OFF + (cf * 16 + lr) * 256 + kk * 32 + lk * 8);
            acc = mfma16(af[kk], bfr, acc);
        }
        float bias_v = bv[cf * 16 + lr];
#pragma unroll
        for (int r = 0; r < 4; r++) {
            vt_s[w * 16 + lk * 4 + r][cf * 16 + lr] = f2bf(acc[r] + bias_v);
        }
    }
    __syncthreads();
    {
        short* vb = ws + VB_OFF + (size_t)b * C_SZ * N_SZ;
        int nn = t & 63;
#pragma unroll
        for (int i = 0; i < 64; i++) {
            int c = (t >> 6) + 4 * i;
            vb[(size_t)c * N_SZ + n0 + nn] = vt_s[nn][c];
        }
    }
}

// ---------------- fused attention: energy -> softmax -> attention write + PV + residual ----------------
__global__ __launch_bounds__(512) void k_attn(const short* __restrict__ ws,
                                              const float* __restrict__ x,
                                              const float* __restrict__ gamma_p,
                                              float* __restrict__ out) {
    __shared__ short v_lds[256][72];    // v tile [c][m], padded (2-way free)
    __shared__ short p_lds[64][72];     // P tile [n][m] bf16, padded
    __shared__ float rsum_s[2][64];
    __shared__ float o_s[64][258];      // O tile staging for transposed write

    const int b = blockIdx.y;
    const int n0 = blockIdx.x * 64;
    const int t = threadIdx.x, w = t >> 6, l = t & 63;
    const int rg = w & 3, ch = w >> 2;       // row-group (16 rows), col-half
    const int lr = l & 15, lk = l >> 4;

    const short* qb = ws + QB_OFF + (size_t)b * N_SZ * DK_SZ;
    const short* kb = ws + KB_OFF + (size_t)b * N_SZ * DK_SZ;
    const short* vb = ws + VB_OFF + (size_t)b * C_SZ * N_SZ;

    // Q fragment for this wave's 16 rows (held in registers all kernel)
    bf16x8 qf = *(const bf16x8*)(qb + (size_t)(n0 + rg * 16 + lr) * DK_SZ + lk * 8);

    // ---- pass 1: row sums of exp(S) (no max subtraction: |S| <= ~40 is fp32-safe) ----
    float rs[4] = {0.f, 0.f, 0.f, 0.f};
    {
        int mb = ch * 32;
        bf16x8 k0 = *(const bf16x8*)(kb + (size_t)(mb + lr) * DK_SZ + lk * 8);
        bf16x8 k1 = *(const bf16x8*)(kb + (size_t)(mb + 16 + lr) * DK_SZ + lk * 8);
        for (int mt = 0; mt < 64; mt++) {
            int mtn = (mt + 1) & 63;
            int mbn = mtn * 64 + ch * 32;
            bf16x8 nk0 = *(const bf16x8*)(kb + (size_t)(mbn + lr) * DK_SZ + lk * 8);
            bf16x8 nk1 = *(const bf16x8*)(kb + (size_t)(mbn + 16 + lr) * DK_SZ + lk * 8);
            f32x4 s0 = {0.f, 0.f, 0.f, 0.f}, s1 = {0.f, 0.f, 0.f, 0.f};
            s0 = mfma16(qf, k0, s0);
            s1 = mfma16(qf, k1, s1);
#pragma unroll
            for (int r = 0; r < 4; r++) rs[r] += __expf(s0[r]) + __expf(s1[r]);
            k0 = nk0; k1 = nk1;
        }
    }
    // reduce across the 16 lanes sharing rows
#pragma unroll
    for (int r = 0; r < 4; r++) {
        rs[r] += __shfl_xor(rs[r], 1);
        rs[r] += __shfl_xor(rs[r], 2);
        rs[r] += __shfl_xor(rs[r], 4);
        rs[r] += __shfl_xor(rs[r], 8);
    }
    if (lr == 0) {
#pragma unroll
        for (int r = 0; r < 4; r++) rsum_s[ch][rg * 16 + lk * 4 + r] = rs[r];
    }
    __syncthreads();
    float inv[4];
#pragma unroll
    for (int r = 0; r < 4; r++) {
        int row = rg * 16 + lk * 4 + r;
        inv[r] = 1.f / (rsum_s[0][row] + rsum_s[1][row]);
    }

    // ---- pass 2: P = exp(S)*inv, write attention, accumulate O = P * v^T ----
    float* attn = out + (size_t)B_SZ * C_SZ * N_SZ + (size_t)b * N_SZ * N_SZ;
    f32x4 O[8];
#pragma unroll
    for (int cb = 0; cb < 8; cb++) O[cb] = (f32x4){0.f, 0.f, 0.f, 0.f};

    for (int mt = 0; mt < 64; mt++) {
        int mb = mt * 64;
        // stage v tile [c][m] (32KB) via 16B chunks
#pragma unroll
        for (int i = 0; i < 4; i++) {
            int chunk = t + 512 * i;           // 0..2047
            int c = chunk >> 3, o8 = chunk & 7;
            u32x4 d = *(const u32x4*)(vb + (size_t)c * N_SZ + mb + o8 * 8);
            *(u32x4*)(&v_lds[c][o8 * 8]) = d;
        }
        // recompute S for this wave's col-half, normalize
        {
            int mbh = mb + ch * 32;
            bf16x8 k0 = *(const bf16x8*)(kb + (size_t)(mbh + lr) * DK_SZ + lk * 8);
            bf16x8 k1 = *(const bf16x8*)(kb + (size_t)(mbh + 16 + lr) * DK_SZ + lk * 8);
            f32x4 s0 = {0.f, 0.f, 0.f, 0.f}, s1 = {0.f, 0.f, 0.f, 0.f};
            s0 = mfma16(qf, k0, s0);
            s1 = mfma16(qf, k1, s1);
#pragma unroll
            for (int r = 0; r < 4; r++) {
                int row = rg * 16 + lk * 4 + r;
                p_lds[row][ch * 32 + lr]      = f2bf(__expf(s0[r]) * inv[r]);
                p_lds[row][ch * 32 + 16 + lr] = f2bf(__expf(s1[r]) * inv[r]);
            }
        }
        __syncthreads();
        // coalesced attention write (float4 x2 per thread)
        {
            int n = t >> 3, m8 = (t & 7) * 8;
            bf16x8 pv = *(const bf16x8*)(&p_lds[n][m8]);
            float* dst = attn + (size_t)(n0 + n) * N_SZ + mb + m8;
            float4 f0, f1;
            f0.x = bf2f(pv[0]); f0.y = bf2f(pv[1]); f0.z = bf2f(pv[2]); f0.w = bf2f(pv[3]);
            f1.x = bf2f(pv[4]); f1.y = bf2f(pv[5]); f1.z = bf2f(pv[6]); f1.w = bf2f(pv[7]);
            *(float4*)dst = f0;
            *(float4*)(dst + 4) = f1;
        }
        // PV: O[16 rows x 128 cols per wave] += P(16x64) @ v^T(64x128)
        {
            bf16x8 a0 = *(const bf16x8*)(&p_lds[rg * 16 + lr][lk * 8]);
            bf16x8 a1 = *(const bf16x8*)(&p_lds[rg * 16 + lr][32 + lk * 8]);
#pragma unroll
            for (int cb = 0; cb < 8; cb++) {
                int cc = ch * 128 + cb * 16 + lr;
                bf16x8 b0 = *(const bf16x8*)(&v_lds[cc][lk * 8]);
                bf16x8 b1 = *(const bf16x8*)(&v_lds[cc][32 + lk * 8]);
                O[cb] = mfma16(a0, b0, O[cb]);
                O[cb] = mfma16(a1, b1, O[cb]);
            }
        }
        __syncthreads();
    }

    // ---- epilogue: out = gamma * O + x, transposed through LDS for coalescing ----
    float g = gamma_p[0];
#pragma unroll
    for (int cb = 0; cb < 8; cb++) {
#pragma unroll
        for (int r = 0; r < 4; r++) {
            o_s[rg * 16 + lk * 4 + r][ch * 128 + cb * 16 + lr] = O[cb][r];
        }
    }
    __syncthreads();
    {
        const float* xb = x + (size_t)b * C_SZ * N_SZ;
        float* ob = out + (size_t)b * C_SZ * N_SZ;
        int nn = t & 63;
#pragma unroll
        for (int i = 0; i < 32; i++) {
            int c = (t >> 6) + 8 * i;
            ob[(size_t)c * N_SZ + n0 + nn] = g * o_s[nn][c] + xb[(size_t)c * N_SZ + n0 + nn];
        }
    }
}

extern "C" void kernel_launch(void* const* d_in, const int* in_sizes, int n_in,
                              void* d_out, int out_size, void* d_ws, size_t ws_size,
                              hipStream_t stream) {
    const float* x     = (const float*)d_in[0];
    const float* Wq    = (const float*)d_in[1];
    const float* bq    = (const float*)d_in[2];
    const float* Wk    = (const float*)d_in[3];
    const float* bk    = (const float*)d_in[4];
    const float* Wv    = (const float*)d_in[5];
    const float* bv    = (const float*)d_in[6];
    const float* gamma = (const float*)d_in[7];
    short* ws = (short*)d_ws;
    float* out = (float*)d_out;

    hipLaunchKernelGGL(k_convw, dim3(256), dim3(256), 0, stream, Wq, Wk, Wv, ws);
    hipLaunchKernelGGL(k_prep, dim3(64, 4), dim3(256), 0, stream, x, bq, bk, bv, ws);
    hipLaunchKernelGGL(k_attn, dim3(64, 4), dim3(512), 0, stream, ws, x, gamma, out);
}

// Round 2
// 165.979 us; speedup vs baseline: 1.0333x; 1.0333x over previous
//
#include <hip/hip_runtime.h>
#include <hip/hip_bf16.h>

typedef __attribute__((ext_vector_type(8))) short bf16x8;
typedef __attribute__((ext_vector_type(4))) float f32x4;
typedef __attribute__((ext_vector_type(4))) unsigned int u32x4;
typedef __attribute__((ext_vector_type(2))) unsigned int u32x2;

#define B_SZ 4
#define C_SZ 256
#define N_SZ 4096
#define DK_SZ 32

// ws layout in bf16 elements
#define WQB_OFF 0
#define WKB_OFF 8192
#define WVB_OFF 16384
#define QB_OFF  81920
#define KB_OFF  606208
#define VB_OFF  1130496

__device__ __forceinline__ short f2bf(float f) {
    union { float f; unsigned int u; } v; v.f = f;
    unsigned int r = v.u + 0x7fffu + ((v.u >> 16) & 1u);
    return (short)(r >> 16);
}

__device__ __forceinline__ unsigned int cvt_pk_bf16(float lo, float hi) {
    unsigned int r;
    asm volatile("v_cvt_pk_bf16_f32 %0, %1, %2" : "=v"(r) : "v"(lo), "v"(hi));
    return r;
}

__device__ __forceinline__ f32x4 mfma16(bf16x8 a, bf16x8 b, f32x4 c) {
    return __builtin_amdgcn_mfma_f32_16x16x32_bf16(a, b, c, 0, 0, 0);
}

__device__ __forceinline__ void gload_lds16(const void* g, void* l) {
    __builtin_amdgcn_global_load_lds((const __attribute__((address_space(1))) unsigned int*)g,
                                     (__attribute__((address_space(3))) unsigned int*)l, 16, 0, 0);
}

// ---------------- weight conversion ----------------
__global__ __launch_bounds__(256) void k_convw(const float* __restrict__ Wq,
                                               const float* __restrict__ Wk,
                                               const float* __restrict__ Wv,
                                               short* __restrict__ ws) {
    int i = blockIdx.x * 256 + threadIdx.x;   // grid = 256 blocks -> i in [0, 65536)
    if (i < 8192) {
        ws[WQB_OFF + i] = f2bf(Wq[i]);
        ws[WKB_OFF + i] = f2bf(Wk[i]);
    }
    ws[WVB_OFF + i] = f2bf(Wv[i]);
}

// ---------------- projection: q, k as [b][n][32] bf16; v as [b][c][n] bf16 ----------------
__global__ __launch_bounds__(256) void k_prep(const float* __restrict__ x,
                                              const float* __restrict__ bq,
                                              const float* __restrict__ bk,
                                              const float* __restrict__ bv,
                                              short* __restrict__ ws) {
    __shared__ short xsT[64][264];   // x^T tile [n][c], padded
    __shared__ short vt_s[64][258];  // v^T tile [n][c] staging for transposed write

    const int b = blockIdx.y;
    const int n0 = blockIdx.x * 64;
    const int t = threadIdx.x;
    const float* xb = x + (size_t)b * C_SZ * N_SZ;

    // stage x tile, transposing to [n][c] bf16
    {
        int c0 = t >> 4, n4 = (t & 15) * 4;
#pragma unroll
        for (int i = 0; i < 16; i++) {
            int c = c0 + 16 * i;
            float4 v = *(const float4*)(xb + (size_t)c * N_SZ + n0 + n4);
            xsT[n4 + 0][c] = f2bf(v.x);
            xsT[n4 + 1][c] = f2bf(v.y);
            xsT[n4 + 2][c] = f2bf(v.z);
            xsT[n4 + 3][c] = f2bf(v.w);
        }
    }
    __syncthreads();

    const int w = t >> 6, l = t & 63;
    const int lr = l & 15, lk = l >> 4;

    // A fragments: rows = this wave's 16 n-rows, 8 contiguous c per lane
    bf16x8 af[8];
#pragma unroll
    for (int kk = 0; kk < 8; kk++)
        af[kk] = *(const bf16x8*)(&xsT[w * 16 + lr][kk * 32 + lk * 8]);

    // Q and K projections: out[n][d], d = 0..31 (2 col-fragments)
#pragma unroll
    for (int qk = 0; qk < 2; qk++) {
        const short* wb = ws + (qk ? WKB_OFF : WQB_OFF);
        const float* bias = qk ? bk : bq;
        short* outp = ws + (qk ? KB_OFF : QB_OFF) + (size_t)b * N_SZ * DK_SZ;
#pragma unroll
        for (int cf = 0; cf < 2; cf++) {
            f32x4 acc = {0.f, 0.f, 0.f, 0.f};
#pragma unroll
            for (int kk = 0; kk < 8; kk++) {
                bf16x8 bfr = *(const bf16x8*)(wb + (cf * 16 + lr) * 256 + kk * 32 + lk * 8);
                acc = mfma16(af[kk], bfr, acc);
            }
            float bias_v = bias[cf * 16 + lr];
#pragma unroll
            for (int r = 0; r < 4; r++) {
                int row = w * 16 + lk * 4 + r;
                outp[(size_t)(n0 + row) * DK_SZ + cf * 16 + lr] = f2bf(acc[r] + bias_v);
            }
        }
    }

    // V projection: v^T[n][c] into LDS, then transposed write to vb[c][n]
#pragma unroll
    for (int cf = 0; cf < 16; cf++) {
        f32x4 acc = {0.f, 0.f, 0.f, 0.f};
#pragma unroll
        for (int kk = 0; kk < 8; kk++) {
            bf16x8 bfr = *(const bf16x8*)(ws + WVB_OFF + (cf * 16 + lr) * 256 + kk * 32 + lk * 8);
            acc = mfma16(af[kk], bfr, acc);
        }
        float bias_v = bv[cf * 16 + lr];
#pragma unroll
        for (int r = 0; r < 4; r++) {
            vt_s[w * 16 + lk * 4 + r][cf * 16 + lr] = f2bf(acc[r] + bias_v);
        }
    }
    __syncthreads();
    {
        short* vb = ws + VB_OFF + (size_t)b * C_SZ * N_SZ;
        int nn = t & 63;
#pragma unroll
        for (int i = 0; i < 64; i++) {
            int c = (t >> 6) + 4 * i;
            vb[(size_t)c * N_SZ + n0 + nn] = vt_s[nn][c];
        }
    }
}

// ---------------- fused attention ----------------
// Block: 512 threads = 8 waves, 64 q-rows. Wave (rg, ch): rg = w&3 row-group
// (16 rows), ch = w>>2. Pass 1: wave (rg,h=ch) sums exp over m-half h,
// barrier-free (swapped mfma(K,Q): lane's 16 values all belong to row n=lr).
// Pass 2 (pipelined, 1 barrier/iter): S'(t+1)+attn-store+P->p_lds[alt] while
// PV(t) reads p_lds[cur] and v_lds[cur]; V staged by global_load_lds with
// pre-swizzled source (j^(c&7)) and swizzled reads.
__global__ __launch_bounds__(512, 1) void k_attn(const short* __restrict__ ws,
                                                 const float* __restrict__ x,
                                                 const float* __restrict__ gamma_p,
                                                 float* __restrict__ out) {
    __shared__ short v_lds[2][256 * 64];   // linear [c][64], swizzled content; 64 KB
    __shared__ short p_lds[2][64][72];     // P tiles (stride 144 B, 16B-aligned); 18.4 KB
    __shared__ float rsum_s[2][64];

    const int b = blockIdx.y;
    const int n0 = blockIdx.x * 64;
    const int t = threadIdx.x, w = t >> 6, l = t & 63;
    const int rg = w & 3, ch = w >> 2;
    const int lr = l & 15, lk = l >> 4;

    const short* qb = ws + QB_OFF + (size_t)b * N_SZ * DK_SZ;
    const short* kb = ws + KB_OFF + (size_t)b * N_SZ * DK_SZ;
    const short* vb = ws + VB_OFF + (size_t)b * C_SZ * N_SZ;

    // Q B-fragment (col j = n = lr), held all kernel
    bf16x8 qf = *(const bf16x8*)(qb + (size_t)(n0 + rg * 16 + lr) * DK_SZ + lk * 8);

    // ---- pass 1: rowsum of exp(S), wave (rg, h=ch) does m-half h, no barriers ----
    float rs = 0.f;
    for (int mt = 0; mt < 32; mt++) {
        int mb = ch * 2048 + mt * 64;
        bf16x8 kf0 = *(const bf16x8*)(kb + (size_t)(mb + lr) * DK_SZ + lk * 8);
        bf16x8 kf1 = *(const bf16x8*)(kb + (size_t)(mb + 16 + lr) * DK_SZ + lk * 8);
        bf16x8 kf2 = *(const bf16x8*)(kb + (size_t)(mb + 32 + lr) * DK_SZ + lk * 8);
        bf16x8 kf3 = *(const bf16x8*)(kb + (size_t)(mb + 48 + lr) * DK_SZ + lk * 8);
        f32x4 s0 = mfma16(kf0, qf, (f32x4){0.f, 0.f, 0.f, 0.f});
        f32x4 s1 = mfma16(kf1, qf, (f32x4){0.f, 0.f, 0.f, 0.f});
        f32x4 s2 = mfma16(kf2, qf, (f32x4){0.f, 0.f, 0.f, 0.f});
        f32x4 s3 = mfma16(kf3, qf, (f32x4){0.f, 0.f, 0.f, 0.f});
#pragma unroll
        for (int r = 0; r < 4; r++)
            rs += __expf(s0[r]) + __expf(s1[r]) + __expf(s2[r]) + __expf(s3[r]);
    }
    rs += __shfl_xor(rs, 16);
    rs += __shfl_xor(rs, 32);
    if (l < 16) rsum_s[ch][rg * 16 + l] = rs;
    __syncthreads();
    const float invp = 1.f / (rsum_s[0][rg * 16 + lr] + rsum_s[1][rg * 16 + lr]);

    // ---- pass 2: pipelined ----
    float* attn = out + (size_t)B_SZ * C_SZ * N_SZ + (size_t)b * N_SZ * N_SZ;
    f32x4 O[8];
#pragma unroll
    for (int cb = 0; cb < 8; cb++) O[cb] = (f32x4){0.f, 0.f, 0.f, 0.f};

    // S'(tt): 2 mfma, exp*invp, float4 attention store, P bf16 -> p_lds[pb]
#define SPRIME(tt, pb)                                                                   \
    {                                                                                    \
        int mbase = (tt) * 64 + ch * 32;                                                 \
        _Pragma("unroll")                                                                \
        for (int t16 = 0; t16 < 2; t16++) {                                              \
            bf16x8 kf = *(const bf16x8*)(kb + (size_t)(mbase + t16 * 16 + lr) * DK_SZ + lk * 8); \
            f32x4 s = mfma16(kf, qf, (f32x4){0.f, 0.f, 0.f, 0.f});                       \
            float4 e;                                                                    \
            e.x = __expf(s[0]) * invp; e.y = __expf(s[1]) * invp;                        \
            e.z = __expf(s[2]) * invp; e.w = __expf(s[3]) * invp;                        \
            *(float4*)(attn + (size_t)(n0 + rg * 16 + lr) * N_SZ + mbase + t16 * 16 + lk * 4) = e; \
            u32x2 pk;                                                                    \
            pk[0] = cvt_pk_bf16(e.x, e.y);                                               \
            pk[1] = cvt_pk_bf16(e.z, e.w);                                               \
            *(u32x2*)(&p_lds[pb][rg * 16 + lr][ch * 32 + t16 * 16 + lk * 4]) = pk;       \
        }                                                                                \
    }

    // stage V tile tt into v_lds[vbuf]: wave w covers c in [w*32, w*32+32)
#define STAGE(tt, vbuf)                                                                  \
    {                                                                                    \
        int mb = (tt) * 64;                                                              \
        _Pragma("unroll")                                                                \
        for (int i = 0; i < 4; i++) {                                                    \
            int c = w * 32 + i * 8 + (l >> 3);                                           \
            int j = l & 7;                                                               \
            const short* g = vb + (size_t)c * N_SZ + mb + ((j ^ (c & 7)) << 3);          \
            gload_lds16(g, (void*)&v_lds[vbuf][(w * 32 + i * 8) * 64]);                  \
        }                                                                                \
    }

    STAGE(0, 0);
    SPRIME(0, 0);

    for (int mt = 0; mt < 64; mt++) {
        __syncthreads();   // stage(mt) + p(mt) visible; readers of alt buffers done
        int cur = mt & 1;
        if (mt < 63) {
            STAGE(mt + 1, cur ^ 1);
            SPRIME(mt + 1, cur ^ 1);
        }
        // PV(mt): O[16 rows x 128 cols] += P(16x64) @ v^T(64x128)
        const char* pbase = (const char*)&p_lds[cur][rg * 16 + lr][0];
        bf16x8 pa0 = *(const bf16x8*)(pbase + lk * 16);
        bf16x8 pa1 = *(const bf16x8*)(pbase + 64 + lk * 16);
        const char* vbase = (const char*)&v_lds[cur][0];
#pragma unroll
        for (int cb = 0; cb < 8; cb++) {
            int c = ch * 128 + cb * 16 + lr;
            int sw = (c & 7) << 4;
            bf16x8 b0 = *(const bf16x8*)(vbase + c * 128 + ((lk << 4) ^ sw));
            bf16x8 b1 = *(const bf16x8*)(vbase + c * 128 + (((4 + lk) << 4) ^ sw));
            O[cb] = mfma16(pa0, b0, O[cb]);
            O[cb] = mfma16(pa1, b1, O[cb]);
        }
    }

    // ---- epilogue: out = gamma*O + x, transposed through LDS (reuse v_lds) ----
    __syncthreads();
    const float g = gamma_p[0];
    float* o_s = (float*)&v_lds[0][0];      // [32][258] f32 = 33 KB
    const float* xb = x + (size_t)b * C_SZ * N_SZ;
    float* ob = out + (size_t)b * C_SZ * N_SZ;
#pragma unroll
    for (int half = 0; half < 2; half++) {
        if ((rg >> 1) == half) {
#pragma unroll
            for (int cb = 0; cb < 8; cb++) {
#pragma unroll
                for (int r = 0; r < 4; r++) {
                    o_s[((rg & 1) * 16 + lk * 4 + r) * 258 + ch * 128 + cb * 16 + lr] = O[cb][r];
                }
            }
        }
        __syncthreads();
        {
            int nn = t & 31;
            int c0 = t >> 5;   // 0..15
#pragma unroll
            for (int i = 0; i < 16; i++) {
                int c = c0 + 16 * i;
                size_t idx = (size_t)c * N_SZ + n0 + half * 32 + nn;
                ob[idx] = g * o_s[nn * 258 + c] + xb[idx];
            }
        }
        __syncthreads();
    }
}

extern "C" void kernel_launch(void* const* d_in, const int* in_sizes, int n_in,
                              void* d_out, int out_size, void* d_ws, size_t ws_size,
                              hipStream_t stream) {
    const float* x     = (const float*)d_in[0];
    const float* Wq    = (const float*)d_in[1];
    const float* bq    = (const float*)d_in[2];
    const float* Wk    = (const float*)d_in[3];
    const float* bk    = (const float*)d_in[4];
    const float* Wv    = (const float*)d_in[5];
    const float* bv    = (const float*)d_in[6];
    const float* gamma = (const float*)d_in[7];
    short* ws = (short*)d_ws;
    float* out = (float*)d_out;

    hipLaunchKernelGGL(k_convw, dim3(256), dim3(256), 0, stream, Wq, Wk, Wv, ws);
    hipLaunchKernelGGL(k_prep, dim3(64, 4), dim3(256), 0, stream, x, bq, bk, bv, ws);
    hipLaunchKernelGGL(k_attn, dim3(64, 4), dim3(512), 0, stream, ws, x, gamma, out);
}

// Round 3
// 155.278 us; speedup vs baseline: 1.1045x; 1.0689x over previous
//
#include <hip/hip_runtime.h>
#include <hip/hip_bf16.h>

typedef __attribute__((ext_vector_type(8))) short bf16x8;
typedef __attribute__((ext_vector_type(4))) float f32x4;
typedef __attribute__((ext_vector_type(4))) unsigned int u32x4;
typedef __attribute__((ext_vector_type(2))) unsigned int u32x2;

#define B_SZ 4
#define C_SZ 256
#define N_SZ 4096
#define DK_SZ 32

// ws layout in bf16 elements
#define WQB_OFF 0
#define WKB_OFF 8192
#define WVB_OFF 16384
#define QB_OFF  81920
#define KB_OFF  606208
#define VB_OFF  1130496

__device__ __forceinline__ short f2bf(float f) {
    union { float f; unsigned int u; } v; v.f = f;
    unsigned int r = v.u + 0x7fffu + ((v.u >> 16) & 1u);
    return (short)(r >> 16);
}

__device__ __forceinline__ unsigned int cvt_pk_bf16(float lo, float hi) {
    unsigned int r;
    asm volatile("v_cvt_pk_bf16_f32 %0, %1, %2" : "=v"(r) : "v"(lo), "v"(hi));
    return r;
}

__device__ __forceinline__ f32x4 mfma16(bf16x8 a, bf16x8 b, f32x4 c) {
    return __builtin_amdgcn_mfma_f32_16x16x32_bf16(a, b, c, 0, 0, 0);
}

__device__ __forceinline__ void gload_lds16(const void* g, void* l) {
    __builtin_amdgcn_global_load_lds((const __attribute__((address_space(1))) unsigned int*)g,
                                     (__attribute__((address_space(3))) unsigned int*)l, 16, 0, 0);
}

// ---------------- weight conversion ----------------
__global__ __launch_bounds__(256) void k_convw(const float* __restrict__ Wq,
                                               const float* __restrict__ Wk,
                                               const float* __restrict__ Wv,
                                               short* __restrict__ ws) {
    int i = blockIdx.x * 256 + threadIdx.x;   // grid = 256 blocks -> i in [0, 65536)
    if (i < 8192) {
        ws[WQB_OFF + i] = f2bf(Wq[i]);
        ws[WKB_OFF + i] = f2bf(Wk[i]);
    }
    ws[WVB_OFF + i] = f2bf(Wv[i]);
}

// ---------------- projection: q, k as [b][n][32] bf16; v as [b][c][n] bf16 ----------------
__global__ __launch_bounds__(256) void k_prep(const float* __restrict__ x,
                                              const float* __restrict__ bq,
                                              const float* __restrict__ bk,
                                              const float* __restrict__ bv,
                                              short* __restrict__ ws) {
    __shared__ short xsT[64][264];   // x^T tile [n][c], padded
    __shared__ short vt_s[64][258];  // v^T tile [n][c] staging for transposed write

    const int b = blockIdx.y;
    const int n0 = blockIdx.x * 64;
    const int t = threadIdx.x;
    const float* xb = x + (size_t)b * C_SZ * N_SZ;

    // stage x tile, transposing to [n][c] bf16
    {
        int c0 = t >> 4, n4 = (t & 15) * 4;
#pragma unroll
        for (int i = 0; i < 16; i++) {
            int c = c0 + 16 * i;
            float4 v = *(const float4*)(xb + (size_t)c * N_SZ + n0 + n4);
            xsT[n4 + 0][c] = f2bf(v.x);
            xsT[n4 + 1][c] = f2bf(v.y);
            xsT[n4 + 2][c] = f2bf(v.z);
            xsT[n4 + 3][c] = f2bf(v.w);
        }
    }
    __syncthreads();

    const int w = t >> 6, l = t & 63;
    const int lr = l & 15, lk = l >> 4;

    // A fragments: rows = this wave's 16 n-rows, 8 contiguous c per lane
    bf16x8 af[8];
#pragma unroll
    for (int kk = 0; kk < 8; kk++)
        af[kk] = *(const bf16x8*)(&xsT[w * 16 + lr][kk * 32 + lk * 8]);

    // Q and K projections: out[n][d], d = 0..31 (2 col-fragments)
#pragma unroll
    for (int qk = 0; qk < 2; qk++) {
        const short* wb = ws + (qk ? WKB_OFF : WQB_OFF);
        const float* bias = qk ? bk : bq;
        short* outp = ws + (qk ? KB_OFF : QB_OFF) + (size_t)b * N_SZ * DK_SZ;
#pragma unroll
        for (int cf = 0; cf < 2; cf++) {
            f32x4 acc = {0.f, 0.f, 0.f, 0.f};
#pragma unroll
            for (int kk = 0; kk < 8; kk++) {
                bf16x8 bfr = *(const bf16x8*)(wb + (cf * 16 + lr) * 256 + kk * 32 + lk * 8);
                acc = mfma16(af[kk], bfr, acc);
            }
            float bias_v = bias[cf * 16 + lr];
#pragma unroll
            for (int r = 0; r < 4; r++) {
                int row = w * 16 + lk * 4 + r;
                outp[(size_t)(n0 + row) * DK_SZ + cf * 16 + lr] = f2bf(acc[r] + bias_v);
            }
        }
    }

    // V projection: v^T[n][c] into LDS, then transposed write to vb[c][n]
#pragma unroll
    for (int cf = 0; cf < 16; cf++) {
        f32x4 acc = {0.f, 0.f, 0.f, 0.f};
#pragma unroll
        for (int kk = 0; kk < 8; kk++) {
            bf16x8 bfr = *(const bf16x8*)(ws + WVB_OFF + (cf * 16 + lr) * 256 + kk * 32 + lk * 8);
            acc = mfma16(af[kk], bfr, acc);
        }
        float bias_v = bv[cf * 16 + lr];
#pragma unroll
        for (int r = 0; r < 4; r++) {
            vt_s[w * 16 + lk * 4 + r][cf * 16 + lr] = f2bf(acc[r] + bias_v);
        }
    }
    __syncthreads();
    {
        short* vb = ws + VB_OFF + (size_t)b * C_SZ * N_SZ;
        int nn = t & 63;
#pragma unroll
        for (int i = 0; i < 64; i++) {
            int c = (t >> 6) + 4 * i;
            vb[(size_t)c * N_SZ + n0 + nn] = vt_s[nn][c];
        }
    }
}

// ---------------- fused attention ----------------
// 512 threads = 8 waves, 64 q-rows/block.
// S'/pass1 mapping: rg = w&3 (n-block of 16), ch = w>>2 (m-half of 32).
// PV mapping:       rp = w&1 (row-half of 32), cp = w>>1 (channel quarter of 64)
//   -> B-fragments shared across 2 row-fragments: 12 ds_read_b128/wave/iter.
// Pipeline: V triple-buffered via global_load_lds staged 2 tiles ahead; P
// double-buffered. One barrier/iter: s_waitcnt vmcnt(6) lgkmcnt(0) leaves the
// 2 attention nt-stores + 4 next-next STAGE loads in flight (order pinned by
// sched_barrier fences: KLOAD -> STAGE -> stores).
__global__ __launch_bounds__(512, 2) void k_attn(const short* __restrict__ ws,
                                                 const float* __restrict__ x,
                                                 const float* __restrict__ gamma_p,
                                                 float* __restrict__ out) {
    __shared__ short v_lds[3][256 * 64];   // linear [c][64], swizzled content; 96 KB
    __shared__ short p_lds[2][64][72];     // P tiles [n][m], stride 144 B; 18.4 KB
    __shared__ float rsum_s[2][64];

    const int b = blockIdx.y;
    const int n0 = blockIdx.x * 64;
    const int t = threadIdx.x, w = t >> 6, l = t & 63;
    const int rg = w & 3, ch = w >> 2;
    const int rp = w & 1, cp = w >> 1;
    const int lr = l & 15, lk = l >> 4;

    const short* qb = ws + QB_OFF + (size_t)b * N_SZ * DK_SZ;
    const short* kb = ws + KB_OFF + (size_t)b * N_SZ * DK_SZ;
    const short* vb = ws + VB_OFF + (size_t)b * C_SZ * N_SZ;

    // Q B-fragment (col j = n = lr), held all kernel
    bf16x8 qf = *(const bf16x8*)(qb + (size_t)(n0 + rg * 16 + lr) * DK_SZ + lk * 8);

    // ---- pass 1: rowsum of exp(S), wave (rg, h=ch) does m-half h, no barriers ----
    float rs = 0.f;
    for (int mt = 0; mt < 32; mt++) {
        int mb = ch * 2048 + mt * 64;
        bf16x8 kfa = *(const bf16x8*)(kb + (size_t)(mb + lr) * DK_SZ + lk * 8);
        bf16x8 kfb = *(const bf16x8*)(kb + (size_t)(mb + 16 + lr) * DK_SZ + lk * 8);
        bf16x8 kfc = *(const bf16x8*)(kb + (size_t)(mb + 32 + lr) * DK_SZ + lk * 8);
        bf16x8 kfd = *(const bf16x8*)(kb + (size_t)(mb + 48 + lr) * DK_SZ + lk * 8);
        f32x4 s0 = mfma16(kfa, qf, (f32x4){0.f, 0.f, 0.f, 0.f});
        f32x4 s1 = mfma16(kfb, qf, (f32x4){0.f, 0.f, 0.f, 0.f});
        f32x4 s2 = mfma16(kfc, qf, (f32x4){0.f, 0.f, 0.f, 0.f});
        f32x4 s3 = mfma16(kfd, qf, (f32x4){0.f, 0.f, 0.f, 0.f});
#pragma unroll
        for (int r = 0; r < 4; r++)
            rs += __expf(s0[r]) + __expf(s1[r]) + __expf(s2[r]) + __expf(s3[r]);
    }
    rs += __shfl_xor(rs, 16);
    rs += __shfl_xor(rs, 32);
    if (l < 16) rsum_s[ch][rg * 16 + l] = rs;
    __syncthreads();
    const float invp = 1.f / (rsum_s[0][rg * 16 + lr] + rsum_s[1][rg * 16 + lr]);

    // ---- pass 2 ----
    float* attn_row = out + (size_t)B_SZ * C_SZ * N_SZ + (size_t)b * N_SZ * N_SZ
                      + (size_t)(n0 + rg * 16 + lr) * N_SZ;
    f32x4 O[2][4];
#pragma unroll
    for (int rf = 0; rf < 2; rf++)
#pragma unroll
        for (int cb = 0; cb < 4; cb++) O[rf][cb] = (f32x4){0.f, 0.f, 0.f, 0.f};

    bf16x8 kf0, kf1;

#define KLOAD(tt)                                                                  \
    {                                                                              \
        const int mbase = (tt) * 64 + ch * 32;                                     \
        kf0 = *(const bf16x8*)(kb + (size_t)(mbase + lr) * DK_SZ + lk * 8);        \
        kf1 = *(const bf16x8*)(kb + (size_t)(mbase + 16 + lr) * DK_SZ + lk * 8);   \
    }

    // stage V tile tt into v_lds[vbuf]: 4 global_load_lds x16B per thread
#define STAGE(tt, vbuf)                                                            \
    {                                                                              \
        const int mb = (tt) * 64;                                                  \
        _Pragma("unroll")                                                          \
        for (int i = 0; i < 4; i++) {                                              \
            int c = w * 32 + i * 8 + (l >> 3);                                     \
            int j = l & 7;                                                         \
            const short* g = vb + (size_t)c * N_SZ + mb + ((j ^ (c & 7)) << 3);    \
            gload_lds16(g, (void*)&v_lds[vbuf][(w * 32 + i * 8) * 64]);            \
        }                                                                          \
    }

    // S' for tile tt: 2 mfma, exp*invp, 2 nt float4 stores, P bf16 -> p_lds[pb]
#define SCOMP(tt, pb)                                                              \
    {                                                                              \
        const int mbase = (tt) * 64 + ch * 32;                                     \
        f32x4 s0 = mfma16(kf0, qf, (f32x4){0.f, 0.f, 0.f, 0.f});                   \
        f32x4 s1 = mfma16(kf1, qf, (f32x4){0.f, 0.f, 0.f, 0.f});                   \
        f32x4 e0, e1;                                                              \
        e0[0] = __expf(s0[0]) * invp; e0[1] = __expf(s0[1]) * invp;                \
        e0[2] = __expf(s0[2]) * invp; e0[3] = __expf(s0[3]) * invp;                \
        e1[0] = __expf(s1[0]) * invp; e1[1] = __expf(s1[1]) * invp;                \
        e1[2] = __expf(s1[2]) * invp; e1[3] = __expf(s1[3]) * invp;                \
        __builtin_nontemporal_store(e0, (f32x4*)(attn_row + mbase + lk * 4));      \
        __builtin_nontemporal_store(e1, (f32x4*)(attn_row + mbase + 16 + lk * 4)); \
        u32x2 pk0, pk1;                                                            \
        pk0[0] = cvt_pk_bf16(e0[0], e0[1]); pk0[1] = cvt_pk_bf16(e0[2], e0[3]);    \
        pk1[0] = cvt_pk_bf16(e1[0], e1[1]); pk1[1] = cvt_pk_bf16(e1[2], e1[3]);    \
        *(u32x2*)(&p_lds[pb][rg * 16 + lr][ch * 32 + lk * 4]) = pk0;               \
        *(u32x2*)(&p_lds[pb][rg * 16 + lr][ch * 32 + 16 + lk * 4]) = pk1;          \
    }

    // prologue: pin order kf -> staging loads -> stores
    KLOAD(0);
    __builtin_amdgcn_sched_barrier(0);
    STAGE(0, 0);
    STAGE(1, 1);
    __builtin_amdgcn_sched_barrier(0);
    SCOMP(0, 0);

    for (int mt = 0; mt < 64; mt++) {
        asm volatile("s_waitcnt vmcnt(6) lgkmcnt(0)" ::: "memory");
        __builtin_amdgcn_sched_barrier(0);
        __builtin_amdgcn_s_barrier();
        __builtin_amdgcn_sched_barrier(0);
        const int cur = mt & 1;
        if (mt < 63) {
            KLOAD(mt + 1);
            __builtin_amdgcn_sched_barrier(0);
            if (mt < 62) STAGE(mt + 2, (mt + 2) % 3);
            __builtin_amdgcn_sched_barrier(0);
            SCOMP(mt + 1, cur ^ 1);
        }
        // PV(mt): O[32 rows x 64 cols per wave] += P(32x64) @ v^T(64x64)
        const int vcur = mt % 3;
        const char* pbase = (const char*)&p_lds[cur][rp * 32 + lr][0];
        bf16x8 a00 = *(const bf16x8*)(pbase + lk * 16);
        bf16x8 a01 = *(const bf16x8*)(pbase + 64 + lk * 16);
        bf16x8 a10 = *(const bf16x8*)(pbase + 2304 + lk * 16);
        bf16x8 a11 = *(const bf16x8*)(pbase + 2304 + 64 + lk * 16);
        const char* vbase = (const char*)&v_lds[vcur][0];
#pragma unroll
        for (int cb = 0; cb < 4; cb++) {
            int c = cp * 64 + cb * 16 + lr;
            int sw = (c & 7) << 4;
            bf16x8 b0 = *(const bf16x8*)(vbase + c * 128 + ((lk << 4) ^ sw));
            bf16x8 b1 = *(const bf16x8*)(vbase + c * 128 + (((4 + lk) << 4) ^ sw));
            O[0][cb] = mfma16(a00, b0, O[0][cb]);
            O[0][cb] = mfma16(a01, b1, O[0][cb]);
            O[1][cb] = mfma16(a10, b0, O[1][cb]);
            O[1][cb] = mfma16(a11, b1, O[1][cb]);
        }
    }
#undef KLOAD
#undef STAGE
#undef SCOMP

    // ---- epilogue: out = gamma*O + x, transposed through LDS (reuse v_lds) ----
    __syncthreads();
    const float g = gamma_p[0];
    float* o_s = (float*)&v_lds[0][0];      // [32][258] f32 = 33 KB
    const float* xb = x + (size_t)b * C_SZ * N_SZ;
    float* ob = out + (size_t)b * C_SZ * N_SZ;
#pragma unroll
    for (int half = 0; half < 2; half++) {
        if (rp == half) {
#pragma unroll
            for (int rf = 0; rf < 2; rf++)
#pragma unroll
                for (int cb = 0; cb < 4; cb++)
#pragma unroll
                    for (int r = 0; r < 4; r++)
                        o_s[(rf * 16 + lk * 4 + r) * 258 + cp * 64 + cb * 16 + lr] = O[rf][cb][r];
        }
        __syncthreads();
        {
            int nn = t & 31;
            int c0 = t >> 5;   // 0..15
#pragma unroll
            for (int i = 0; i < 16; i++) {
                int c = c0 + 16 * i;
                size_t idx = (size_t)c * N_SZ + n0 + half * 32 + nn;
                ob[idx] = g * o_s[nn * 258 + c] + xb[idx];
            }
        }
        __syncthreads();
    }
}

extern "C" void kernel_launch(void* const* d_in, const int* in_sizes, int n_in,
                              void* d_out, int out_size, void* d_ws, size_t ws_size,
                              hipStream_t stream) {
    const float* x     = (const float*)d_in[0];
    const float* Wq    = (const float*)d_in[1];
    const float* bq    = (const float*)d_in[2];
    const float* Wk    = (const float*)d_in[3];
    const float* bk    = (const float*)d_in[4];
    const float* Wv    = (const float*)d_in[5];
    const float* bv    = (const float*)d_in[6];
    const float* gamma = (const float*)d_in[7];
    short* ws = (short*)d_ws;
    float* out = (float*)d_out;

    hipLaunchKernelGGL(k_convw, dim3(256), dim3(256), 0, stream, Wq, Wk, Wv, ws);
    hipLaunchKernelGGL(k_prep, dim3(64, 4), dim3(256), 0, stream, x, bq, bk, bv, ws);
    hipLaunchKernelGGL(k_attn, dim3(64, 4), dim3(512), 0, stream, ws, x, gamma, out);
}

// Round 4
// 147.074 us; speedup vs baseline: 1.1661x; 1.0558x over previous
//
#include <hip/hip_runtime.h>
#include <hip/hip_bf16.h>

typedef __attribute__((ext_vector_type(8))) short bf16x8;
typedef __attribute__((ext_vector_type(4))) float f32x4;
typedef __attribute__((ext_vector_type(4))) unsigned int u32x4;
typedef __attribute__((ext_vector_type(2))) unsigned int u32x2;

#define B_SZ 4
#define C_SZ 256
#define N_SZ 4096
#define DK_SZ 32

// ws layout in bf16 elements
#define WQB_OFF 0
#define WKB_OFF 8192
#define WVB_OFF 16384
#define QB_OFF  81920
#define KB_OFF  606208
#define VB_OFF  1130496

__device__ __forceinline__ short f2bf(float f) {
    union { float f; unsigned int u; } v; v.f = f;
    unsigned int r = v.u + 0x7fffu + ((v.u >> 16) & 1u);
    return (short)(r >> 16);
}

__device__ __forceinline__ unsigned int cvt_pk_bf16(float lo, float hi) {
    unsigned int r;
    asm volatile("v_cvt_pk_bf16_f32 %0, %1, %2" : "=v"(r) : "v"(lo), "v"(hi));
    return r;
}

__device__ __forceinline__ f32x4 mfma16(bf16x8 a, bf16x8 b, f32x4 c) {
    return __builtin_amdgcn_mfma_f32_16x16x32_bf16(a, b, c, 0, 0, 0);
}

__device__ __forceinline__ void gload_lds16(const void* g, void* l) {
    __builtin_amdgcn_global_load_lds((const __attribute__((address_space(1))) unsigned int*)g,
                                     (__attribute__((address_space(3))) unsigned int*)l, 16, 0, 0);
}

// XCD-affinity remap: grid = 256 1D, block i -> XCD i%8 (round-robin).
// Batch b owns XCDs {2b, 2b+1} -> per-XCD working set (V_b 2MB + K_b + Q_b) < 4MB L2.
__device__ __forceinline__ void remap_block(int i, int& b, int& n0) {
    b = (i & 7) >> 1;
    n0 = (((i >> 3) << 1) | (i & 1)) * 64;
}

// ---------------- weight conversion ----------------
__global__ __launch_bounds__(256) void k_convw(const float* __restrict__ Wq,
                                               const float* __restrict__ Wk,
                                               const float* __restrict__ Wv,
                                               short* __restrict__ ws) {
    int i = blockIdx.x * 256 + threadIdx.x;   // grid = 256 blocks -> i in [0, 65536)
    if (i < 8192) {
        ws[WQB_OFF + i] = f2bf(Wq[i]);
        ws[WKB_OFF + i] = f2bf(Wk[i]);
    }
    ws[WVB_OFF + i] = f2bf(Wv[i]);
}

// ---------------- projection: q, k as [b][n][32] bf16; v as [b][c][n] bf16 ----------------
__global__ __launch_bounds__(256) void k_prep(const float* __restrict__ x,
                                              const float* __restrict__ bq,
                                              const float* __restrict__ bk,
                                              const float* __restrict__ bv,
                                              short* __restrict__ ws) {
    __shared__ short xsT[64][264];   // x^T tile [n][c], padded
    __shared__ short vt_s[64][258];  // v^T tile [n][c] staging for transposed write

    int b, n0;
    remap_block(blockIdx.x, b, n0);
    const int t = threadIdx.x;
    const float* xb = x + (size_t)b * C_SZ * N_SZ;

    // stage x tile, transposing to [n][c] bf16
    {
        int c0 = t >> 4, n4 = (t & 15) * 4;
#pragma unroll
        for (int i = 0; i < 16; i++) {
            int c = c0 + 16 * i;
            float4 v = *(const float4*)(xb + (size_t)c * N_SZ + n0 + n4);
            xsT[n4 + 0][c] = f2bf(v.x);
            xsT[n4 + 1][c] = f2bf(v.y);
            xsT[n4 + 2][c] = f2bf(v.z);
            xsT[n4 + 3][c] = f2bf(v.w);
        }
    }
    __syncthreads();

    const int w = t >> 6, l = t & 63;
    const int lr = l & 15, lk = l >> 4;

    // A fragments: rows = this wave's 16 n-rows, 8 contiguous c per lane
    bf16x8 af[8];
#pragma unroll
    for (int kk = 0; kk < 8; kk++)
        af[kk] = *(const bf16x8*)(&xsT[w * 16 + lr][kk * 32 + lk * 8]);

    // Q and K projections: out[n][d], d = 0..31 (2 col-fragments)
#pragma unroll
    for (int qk = 0; qk < 2; qk++) {
        const short* wb = ws + (qk ? WKB_OFF : WQB_OFF);
        const float* bias = qk ? bk : bq;
        short* outp = ws + (qk ? KB_OFF : QB_OFF) + (size_t)b * N_SZ * DK_SZ;
#pragma unroll
        for (int cf = 0; cf < 2; cf++) {
            f32x4 acc = {0.f, 0.f, 0.f, 0.f};
#pragma unroll
            for (int kk = 0; kk < 8; kk++) {
                bf16x8 bfr = *(const bf16x8*)(wb + (cf * 16 + lr) * 256 + kk * 32 + lk * 8);
                acc = mfma16(af[kk], bfr, acc);
            }
            float bias_v = bias[cf * 16 + lr];
#pragma unroll
            for (int r = 0; r < 4; r++) {
                int row = w * 16 + lk * 4 + r;
                outp[(size_t)(n0 + row) * DK_SZ + cf * 16 + lr] = f2bf(acc[r] + bias_v);
            }
        }
    }

    // V projection: v^T[n][c] into LDS, then transposed write to vb[c][n]
#pragma unroll
    for (int cf = 0; cf < 16; cf++) {
        f32x4 acc = {0.f, 0.f, 0.f, 0.f};
#pragma unroll
        for (int kk = 0; kk < 8; kk++) {
            bf16x8 bfr = *(const bf16x8*)(ws + WVB_OFF + (cf * 16 + lr) * 256 + kk * 32 + lk * 8);
            acc = mfma16(af[kk], bfr, acc);
        }
        float bias_v = bv[cf * 16 + lr];
#pragma unroll
        for (int r = 0; r < 4; r++) {
            vt_s[w * 16 + lk * 4 + r][cf * 16 + lr] = f2bf(acc[r] + bias_v);
        }
    }
    __syncthreads();
    {
        short* vb = ws + VB_OFF + (size_t)b * C_SZ * N_SZ;
        int nn = t & 63;
#pragma unroll
        for (int i = 0; i < 64; i++) {
            int c = (t >> 6) + 4 * i;
            vb[(size_t)c * N_SZ + n0 + nn] = vt_s[nn][c];
        }
    }
}

// ---------------- fused attention ----------------
// 512 threads = 8 waves. S' mapping: rg=w&3 (16 rows), ch=w>>2 (m-half).
// PV mapping: rp=w&1 (32-row half), cp=w>>1 (64-col quarter).
// Schedule (one barrier/iter, all vm waits counted):
//   barrier[vmcnt(2) lgkmcnt(0)]  -> guarantees STAGE(mt+1) (K+V) landed;
//                                    only stores(mt) may remain in flight.
//   SCOMP_CALC(mt+1): k from LDS, mfma, exp, cvt, p_lds write; e kept in regs
//   STAGE(mt+2): 1 K-gload_lds + 4 V-gload_lds   (issued BEFORE stores!)
//   SSTORE(mt+1): 2 nontemporal attn stores
//   PV(mt): ds_reads + 16 mfma
// In-order vmcnt retire: STAGE ops are always older than the following
// stores, so the barrier's vmcnt(2) never waits on a store ack; stores get
// ~1.7 iterations to complete. No compiler-tracked vm dependencies remain.
__global__ __launch_bounds__(512, 1) void k_attn(const short* __restrict__ ws,
                                                 const float* __restrict__ x,
                                                 const float* __restrict__ gamma_p,
                                                 float* __restrict__ out) {
    __shared__ short v_lds[3][16384];      // V tiles, linear [c][64] swizzled; 96 KB
    __shared__ short k_lds[3][2304];       // K tiles [64][32] row-major +512B overlap pad; 13.5 KB
    __shared__ short p_lds[2][64][72];     // P tiles [n][m], stride 144 B; 18 KB
    __shared__ float rsum_s[2][64];

    int b, n0;
    remap_block(blockIdx.x, b, n0);
    const int t = threadIdx.x, w = t >> 6, l = t & 63;
    const int rg = w & 3, ch = w >> 2;
    const int rp = w & 1, cp = w >> 1;
    const int lr = l & 15, lk = l >> 4;

    const short* qb = ws + QB_OFF + (size_t)b * N_SZ * DK_SZ;
    const short* kb = ws + KB_OFF + (size_t)b * N_SZ * DK_SZ;
    const short* vb = ws + VB_OFF + (size_t)b * C_SZ * N_SZ;
    const char* kbb = (const char*)kb;

    // Q B-fragment (col j = n = lr), held all kernel
    bf16x8 qf = *(const bf16x8*)(qb + (size_t)(n0 + rg * 16 + lr) * DK_SZ + lk * 8);

    // ---- pass 1: rowsum of exp(S), wave (rg, h=ch) does m-half h, no barriers ----
    // rg-duplicate K loads hit L1; K_b is L2-resident via XCD affinity.
    float rs = 0.f;
    for (int mt = 0; mt < 32; mt++) {
        int mb = ch * 2048 + mt * 64;
        bf16x8 kfa = *(const bf16x8*)(kb + (size_t)(mb + lr) * DK_SZ + lk * 8);
        bf16x8 kfb = *(const bf16x8*)(kb + (size_t)(mb + 16 + lr) * DK_SZ + lk * 8);
        bf16x8 kfc = *(const bf16x8*)(kb + (size_t)(mb + 32 + lr) * DK_SZ + lk * 8);
        bf16x8 kfd = *(const bf16x8*)(kb + (size_t)(mb + 48 + lr) * DK_SZ + lk * 8);
        f32x4 s0 = mfma16(kfa, qf, (f32x4){0.f, 0.f, 0.f, 0.f});
        f32x4 s1 = mfma16(kfb, qf, (f32x4){0.f, 0.f, 0.f, 0.f});
        f32x4 s2 = mfma16(kfc, qf, (f32x4){0.f, 0.f, 0.f, 0.f});
        f32x4 s3 = mfma16(kfd, qf, (f32x4){0.f, 0.f, 0.f, 0.f});
#pragma unroll
        for (int r = 0; r < 4; r++)
            rs += __expf(s0[r]) + __expf(s1[r]) + __expf(s2[r]) + __expf(s3[r]);
    }
    rs += __shfl_xor(rs, 16);
    rs += __shfl_xor(rs, 32);
    if (l < 16) rsum_s[ch][rg * 16 + l] = rs;
    __syncthreads();
    const float invp = 1.f / (rsum_s[0][rg * 16 + lr] + rsum_s[1][rg * 16 + lr]);

    // ---- pass 2 ----
    float* attn_row = out + (size_t)B_SZ * C_SZ * N_SZ + (size_t)b * N_SZ * N_SZ
                      + (size_t)(n0 + rg * 16 + lr) * N_SZ;
    f32x4 O[2][4];
#pragma unroll
    for (int rf = 0; rf < 2; rf++)
#pragma unroll
        for (int cb = 0; cb < 4; cb++) O[rf][cb] = (f32x4){0.f, 0.f, 0.f, 0.f};

    f32x4 e0, e1;
    int sc_mbase = 0;

    // stage K(tt)+V(tt) into buffers [tt%3]: 5 gload_lds per thread, K first.
    // K tile = 4 KB contiguous; wave w loads bytes [w*512, w*512+1024) (upper
    // half duplicates wave w+1's lower half - benign same-value LDS race).
#define STAGE(tt, buf)                                                             \
    {                                                                              \
        gload_lds16(kbb + (size_t)(tt) * 4096 + w * 512 + l * 16,                  \
                    (void*)&k_lds[buf][w * 256]);                                  \
        const int mb = (tt) * 64;                                                  \
        _Pragma("unroll")                                                          \
        for (int i = 0; i < 4; i++) {                                              \
            int c = w * 32 + i * 8 + (l >> 3);                                     \
            int j = l & 7;                                                         \
            const short* g = vb + (size_t)c * N_SZ + mb + ((j ^ (c & 7)) << 3);    \
            gload_lds16(g, (void*)&v_lds[buf][(w * 32 + i * 8) * 64]);             \
        }                                                                          \
    }

    // S' for tile tt: k from k_lds, 2 mfma, exp*invp, cvt+p_lds write; e kept.
#define SCOMP_CALC(tt, pb)                                                         \
    {                                                                              \
        sc_mbase = (tt) * 64 + ch * 32;                                            \
        const char* kl = (const char*)&k_lds[(tt) % 3][0];                         \
        bf16x8 kf0 = *(const bf16x8*)(kl + (ch * 32 + lr) * 64 + lk * 16);         \
        bf16x8 kf1 = *(const bf16x8*)(kl + (ch * 32 + 16 + lr) * 64 + lk * 16);    \
        f32x4 s0 = mfma16(kf0, qf, (f32x4){0.f, 0.f, 0.f, 0.f});                   \
        f32x4 s1 = mfma16(kf1, qf, (f32x4){0.f, 0.f, 0.f, 0.f});                   \
        e0[0] = __expf(s0[0]) * invp; e0[1] = __expf(s0[1]) * invp;                \
        e0[2] = __expf(s0[2]) * invp; e0[3] = __expf(s0[3]) * invp;                \
        e1[0] = __expf(s1[0]) * invp; e1[1] = __expf(s1[1]) * invp;                \
        e1[2] = __expf(s1[2]) * invp; e1[3] = __expf(s1[3]) * invp;                \
        u32x2 pk0, pk1;                                                            \
        pk0[0] = cvt_pk_bf16(e0[0], e0[1]); pk0[1] = cvt_pk_bf16(e0[2], e0[3]);    \
        pk1[0] = cvt_pk_bf16(e1[0], e1[1]); pk1[1] = cvt_pk_bf16(e1[2], e1[3]);    \
        *(u32x2*)(&p_lds[pb][rg * 16 + lr][ch * 32 + lk * 4]) = pk0;               \
        *(u32x2*)(&p_lds[pb][rg * 16 + lr][ch * 32 + 16 + lk * 4]) = pk1;          \
    }

#define SSTORE()                                                                   \
    {                                                                              \
        __builtin_nontemporal_store(e0, (f32x4*)(attn_row + sc_mbase + lk * 4));   \
        __builtin_nontemporal_store(e1, (f32x4*)(attn_row + sc_mbase + 16 + lk * 4)); \
    }

    // prologue
    STAGE(0, 0);
    STAGE(1, 1);
    __builtin_amdgcn_sched_barrier(0);
    asm volatile("s_waitcnt vmcnt(9)" ::: "memory");   // K(0) landed
    __builtin_amdgcn_sched_barrier(0);
    SCOMP_CALC(0, 0);
    SSTORE();

    for (int mt = 0; mt < 64; mt++) {
        asm volatile("s_waitcnt vmcnt(2) lgkmcnt(0)" ::: "memory");
        __builtin_amdgcn_sched_barrier(0);
        __builtin_amdgcn_s_barrier();
        __builtin_amdgcn_sched_barrier(0);
        const int cur = mt & 1;
        if (mt < 63) SCOMP_CALC(mt + 1, cur ^ 1);
        __builtin_amdgcn_sched_barrier(0);
        if (mt < 62) STAGE(mt + 2, (mt + 2) % 3);
        __builtin_amdgcn_sched_barrier(0);
        if (mt < 63) SSTORE();
        __builtin_amdgcn_sched_barrier(0);
        // PV(mt): O[32 rows x 64 cols per wave] += P(32x64) @ v^T(64x64)
        const int vcur = mt % 3;
        const char* pbase = (const char*)&p_lds[cur][rp * 32 + lr][0];
        bf16x8 a00 = *(const bf16x8*)(pbase + lk * 16);
        bf16x8 a01 = *(const bf16x8*)(pbase + 64 + lk * 16);
        bf16x8 a10 = *(const bf16x8*)(pbase + 2304 + lk * 16);
        bf16x8 a11 = *(const bf16x8*)(pbase + 2304 + 64 + lk * 16);
        const char* vbase = (const char*)&v_lds[vcur][0];
#pragma unroll
        for (int cb = 0; cb < 4; cb++) {
            int c = cp * 64 + cb * 16 + lr;
            int sw = (c & 7) << 4;
            bf16x8 b0 = *(const bf16x8*)(vbase + c * 128 + ((lk << 4) ^ sw));
            bf16x8 b1 = *(const bf16x8*)(vbase + c * 128 + (((4 + lk) << 4) ^ sw));
            O[0][cb] = mfma16(a00, b0, O[0][cb]);
            O[0][cb] = mfma16(a01, b1, O[0][cb]);
            O[1][cb] = mfma16(a10, b0, O[1][cb]);
            O[1][cb] = mfma16(a11, b1, O[1][cb]);
        }
    }
#undef STAGE
#undef SCOMP_CALC
#undef SSTORE

    // ---- epilogue: out = gamma*O + x, transposed through LDS (reuse v_lds) ----
    __syncthreads();
    const float g = gamma_p[0];
    float* o_s = (float*)&v_lds[0][0];      // [32][258] f32 = 33 KB
    const float* xb = x + (size_t)b * C_SZ * N_SZ;
    float* ob = out + (size_t)b * C_SZ * N_SZ;
#pragma unroll
    for (int half = 0; half < 2; half++) {
        if (rp == half) {
#pragma unroll
            for (int rf = 0; rf < 2; rf++)
#pragma unroll
                for (int cb = 0; cb < 4; cb++)
#pragma unroll
                    for (int r = 0; r < 4; r++)
                        o_s[(rf * 16 + lk * 4 + r) * 258 + cp * 64 + cb * 16 + lr] = O[rf][cb][r];
        }
        __syncthreads();
        {
            int nn = t & 31;
            int c0 = t >> 5;   // 0..15
#pragma unroll
            for (int i = 0; i < 16; i++) {
                int c = c0 + 16 * i;
                size_t idx = (size_t)c * N_SZ + n0 + half * 32 + nn;
                ob[idx] = g * o_s[nn * 258 + c] + xb[idx];
            }
        }
        __syncthreads();
    }
}

extern "C" void kernel_launch(void* const* d_in, const int* in_sizes, int n_in,
                              void* d_out, int out_size, void* d_ws, size_t ws_size,
                              hipStream_t stream) {
    const float* x     = (const float*)d_in[0];
    const float* Wq    = (const float*)d_in[1];
    const float* bq    = (const float*)d_in[2];
    const float* Wk    = (const float*)d_in[3];
    const float* bk    = (const float*)d_in[4];
    const float* Wv    = (const float*)d_in[5];
    const float* bv    = (const float*)d_in[6];
    const float* gamma = (const float*)d_in[7];
    short* ws = (short*)d_ws;
    float* out = (float*)d_out;

    hipLaunchKernelGGL(k_convw, dim3(256), dim3(256), 0, stream, Wq, Wk, Wv, ws);
    hipLaunchKernelGGL(k_prep, dim3(256), dim3(256), 0, stream, x, bq, bk, bv, ws);
    hipLaunchKernelGGL(k_attn, dim3(256), dim3(512), 0, stream, ws, x, gamma, out);
}

// Round 5
// 141.999 us; speedup vs baseline: 1.2078x; 1.0357x over previous
//
#include <hip/hip_runtime.h>
#include <hip/hip_bf16.h>

typedef __attribute__((ext_vector_type(8))) short bf16x8;
typedef __attribute__((ext_vector_type(4))) float f32x4;
typedef __attribute__((ext_vector_type(4))) unsigned int u32x4;
typedef __attribute__((ext_vector_type(2))) unsigned int u32x2;

#define B_SZ 4
#define C_SZ 256
#define N_SZ 4096
#define DK_SZ 32

// ws layout in bf16 elements
#define WQB_OFF 0
#define WKB_OFF 8192
#define WVB_OFF 16384
#define QB_OFF  81920
#define KB_OFF  606208
#define VB_OFF  1130496

__device__ __forceinline__ short f2bf(float f) {
    union { float f; unsigned int u; } v; v.f = f;
    unsigned int r = v.u + 0x7fffu + ((v.u >> 16) & 1u);
    return (short)(r >> 16);
}

__device__ __forceinline__ float asf(unsigned int u) {
    union { unsigned int u; float f; } v; v.u = u;
    return v.f;
}

__device__ __forceinline__ unsigned int cvt_pk_bf16(float lo, float hi) {
    unsigned int r;
    asm volatile("v_cvt_pk_bf16_f32 %0, %1, %2" : "=v"(r) : "v"(lo), "v"(hi));
    return r;
}

__device__ __forceinline__ f32x4 mfma16(bf16x8 a, bf16x8 b, f32x4 c) {
    return __builtin_amdgcn_mfma_f32_16x16x32_bf16(a, b, c, 0, 0, 0);
}

__device__ __forceinline__ void gload_lds16(const void* g, void* l) {
    __builtin_amdgcn_global_load_lds((const __attribute__((address_space(1))) unsigned int*)g,
                                     (__attribute__((address_space(3))) unsigned int*)l, 16, 0, 0);
}

// XCD-affinity remap: grid = 256 1D, block i -> XCD i%8 (round-robin).
// Batch b owns XCDs {2b, 2b+1} -> per-XCD working set (V_b 2MB + K_b + Q_b) < 4MB L2.
__device__ __forceinline__ void remap_block(int i, int& b, int& n0) {
    b = (i & 7) >> 1;
    n0 = (((i >> 3) << 1) | (i & 1)) * 64;
}

// ---------------- weight conversion ----------------
__global__ __launch_bounds__(256) void k_convw(const float* __restrict__ Wq,
                                               const float* __restrict__ Wk,
                                               const float* __restrict__ Wv,
                                               short* __restrict__ ws) {
    int i = blockIdx.x * 256 + threadIdx.x;   // grid = 256 blocks -> i in [0, 65536)
    if (i < 8192) {
        ws[WQB_OFF + i] = f2bf(Wq[i]);
        ws[WKB_OFF + i] = f2bf(Wk[i]);
    }
    ws[WVB_OFF + i] = f2bf(Wv[i]);
}

// ---------------- projection: q, k as [b][n][32] bf16; v as [b][c][n] bf16 ----------------
__global__ __launch_bounds__(256) void k_prep(const float* __restrict__ x,
                                              const float* __restrict__ bq,
                                              const float* __restrict__ bk,
                                              const float* __restrict__ bv,
                                              short* __restrict__ ws) {
    __shared__ short xsT[64][264];   // x^T tile [n][c], padded
    __shared__ short vt_s[64][258];  // v^T tile [n][c] staging for transposed write

    int b, n0;
    remap_block(blockIdx.x, b, n0);
    const int t = threadIdx.x;
    const float* xb = x + (size_t)b * C_SZ * N_SZ;

    // stage x tile, transposing to [n][c] bf16
    {
        int c0 = t >> 4, n4 = (t & 15) * 4;
#pragma unroll
        for (int i = 0; i < 16; i++) {
            int c = c0 + 16 * i;
            float4 v = *(const float4*)(xb + (size_t)c * N_SZ + n0 + n4);
            xsT[n4 + 0][c] = f2bf(v.x);
            xsT[n4 + 1][c] = f2bf(v.y);
            xsT[n4 + 2][c] = f2bf(v.z);
            xsT[n4 + 3][c] = f2bf(v.w);
        }
    }
    __syncthreads();

    const int w = t >> 6, l = t & 63;
    const int lr = l & 15, lk = l >> 4;

    // A fragments: rows = this wave's 16 n-rows, 8 contiguous c per lane
    bf16x8 af[8];
#pragma unroll
    for (int kk = 0; kk < 8; kk++)
        af[kk] = *(const bf16x8*)(&xsT[w * 16 + lr][kk * 32 + lk * 8]);

    // Q and K projections: out[n][d], d = 0..31 (2 col-fragments)
#pragma unroll
    for (int qk = 0; qk < 2; qk++) {
        const short* wb = ws + (qk ? WKB_OFF : WQB_OFF);
        const float* bias = qk ? bk : bq;
        short* outp = ws + (qk ? KB_OFF : QB_OFF) + (size_t)b * N_SZ * DK_SZ;
#pragma unroll
        for (int cf = 0; cf < 2; cf++) {
            f32x4 acc = {0.f, 0.f, 0.f, 0.f};
#pragma unroll
            for (int kk = 0; kk < 8; kk++) {
                bf16x8 bfr = *(const bf16x8*)(wb + (cf * 16 + lr) * 256 + kk * 32 + lk * 8);
                acc = mfma16(af[kk], bfr, acc);
            }
            float bias_v = bias[cf * 16 + lr];
#pragma unroll
            for (int r = 0; r < 4; r++) {
                int row = w * 16 + lk * 4 + r;
                outp[(size_t)(n0 + row) * DK_SZ + cf * 16 + lr] = f2bf(acc[r] + bias_v);
            }
        }
    }

    // V projection: v^T[n][c] into LDS, then transposed write to vb[c][n]
#pragma unroll
    for (int cf = 0; cf < 16; cf++) {
        f32x4 acc = {0.f, 0.f, 0.f, 0.f};
#pragma unroll
        for (int kk = 0; kk < 8; kk++) {
            bf16x8 bfr = *(const bf16x8*)(ws + WVB_OFF + (cf * 16 + lr) * 256 + kk * 32 + lk * 8);
            acc = mfma16(af[kk], bfr, acc);
        }
        float bias_v = bv[cf * 16 + lr];
#pragma unroll
        for (int r = 0; r < 4; r++) {
            vt_s[w * 16 + lk * 4 + r][cf * 16 + lr] = f2bf(acc[r] + bias_v);
        }
    }
    __syncthreads();
    {
        short* vb = ws + VB_OFF + (size_t)b * C_SZ * N_SZ;
        int nn = t & 63;
#pragma unroll
        for (int i = 0; i < 64; i++) {
            int c = (t >> 6) + 4 * i;
            vb[(size_t)c * N_SZ + n0 + nn] = vt_s[nn][c];
        }
    }
}

// ---------------- fused attention ----------------
// 512 threads = 8 waves. S' mapping: rg=w&3 (16 rows), ch=w>>2 (m-half).
// PV mapping: rp=w&1 (32-row half), cp=w>>1 (64-col quarter).
// Per iter: barrier[vmcnt(2) lgkmcnt(0)] -> SCOMP(mt+1) [k_lds mfma, exp,
// P->p_lds alt] -> STAGE(mt+2) [5 gload_lds] -> ASTORE(mt) [p_lds -> full-line
// nt stores] -> PV(mt). Stores are the 2 newest vm ops each iter, so the
// barrier's vmcnt(2) never waits on a store ack (~1 iter of slack).
// ASTORE mapping: lane l of wave w -> row w*8+(l>>3), cols (l&7)*4; each
// 8-lane group writes one aligned 128B line per instruction.
__global__ __launch_bounds__(512, 1) void k_attn(const short* __restrict__ ws,
                                                 const float* __restrict__ x,
                                                 const float* __restrict__ gamma_p,
                                                 float* __restrict__ out) {
    __shared__ short v_lds[3][16384];      // V tiles, linear [c][64] swizzled; 96 KB
    __shared__ short k_lds[3][2304];       // K tiles [64][32] row-major +512B overlap pad; 13.8 KB
    __shared__ short p_lds[2][64][72];     // P tiles [n][m], stride 144 B; 18 KB
    __shared__ float rsum_s[2][64];

    int b, n0;
    remap_block(blockIdx.x, b, n0);
    const int t = threadIdx.x, w = t >> 6, l = t & 63;
    const int rg = w & 3, ch = w >> 2;
    const int rp = w & 1, cp = w >> 1;
    const int lr = l & 15, lk = l >> 4;

    const short* qb = ws + QB_OFF + (size_t)b * N_SZ * DK_SZ;
    const short* kb = ws + KB_OFF + (size_t)b * N_SZ * DK_SZ;
    const short* vb = ws + VB_OFF + (size_t)b * C_SZ * N_SZ;
    const char* kbb = (const char*)kb;

    // Q B-fragment (col j = n = lr), held all kernel
    bf16x8 qf = *(const bf16x8*)(qb + (size_t)(n0 + rg * 16 + lr) * DK_SZ + lk * 8);

    // ---- pass 1: rowsum of exp(S), wave (rg, h=ch) does m-half h, no barriers ----
    float rs = 0.f;
    for (int mt = 0; mt < 32; mt++) {
        int mb = ch * 2048 + mt * 64;
        bf16x8 kfa = *(const bf16x8*)(kb + (size_t)(mb + lr) * DK_SZ + lk * 8);
        bf16x8 kfb = *(const bf16x8*)(kb + (size_t)(mb + 16 + lr) * DK_SZ + lk * 8);
        bf16x8 kfc = *(const bf16x8*)(kb + (size_t)(mb + 32 + lr) * DK_SZ + lk * 8);
        bf16x8 kfd = *(const bf16x8*)(kb + (size_t)(mb + 48 + lr) * DK_SZ + lk * 8);
        f32x4 s0 = mfma16(kfa, qf, (f32x4){0.f, 0.f, 0.f, 0.f});
        f32x4 s1 = mfma16(kfb, qf, (f32x4){0.f, 0.f, 0.f, 0.f});
        f32x4 s2 = mfma16(kfc, qf, (f32x4){0.f, 0.f, 0.f, 0.f});
        f32x4 s3 = mfma16(kfd, qf, (f32x4){0.f, 0.f, 0.f, 0.f});
#pragma unroll
        for (int r = 0; r < 4; r++)
            rs += __expf(s0[r]) + __expf(s1[r]) + __expf(s2[r]) + __expf(s3[r]);
    }
    rs += __shfl_xor(rs, 16);
    rs += __shfl_xor(rs, 32);
    if (l < 16) rsum_s[ch][rg * 16 + l] = rs;
    __syncthreads();
    const float invp = 1.f / (rsum_s[0][rg * 16 + lr] + rsum_s[1][rg * 16 + lr]);

    // ---- pass 2 ----
    float* attn_b = out + (size_t)B_SZ * C_SZ * N_SZ + (size_t)b * N_SZ * N_SZ;
    f32x4 O[2][4];
#pragma unroll
    for (int rf = 0; rf < 2; rf++)
#pragma unroll
        for (int cb = 0; cb < 4; cb++) O[rf][cb] = (f32x4){0.f, 0.f, 0.f, 0.f};

    // stage K(tt)+V(tt) into buffers [tt%3]: 5 gload_lds per thread, K first.
#define STAGE(tt, buf)                                                             \
    {                                                                              \
        gload_lds16(kbb + (size_t)(tt) * 4096 + w * 512 + l * 16,                  \
                    (void*)&k_lds[buf][w * 256]);                                  \
        const int mb = (tt) * 64;                                                  \
        _Pragma("unroll")                                                          \
        for (int i = 0; i < 4; i++) {                                              \
            int c = w * 32 + i * 8 + (l >> 3);                                     \
            int j = l & 7;                                                         \
            const short* g = vb + (size_t)c * N_SZ + mb + ((j ^ (c & 7)) << 3);    \
            gload_lds16(g, (void*)&v_lds[buf][(w * 32 + i * 8) * 64]);             \
        }                                                                          \
    }

    // S' for tile tt: k from k_lds, 2 mfma, exp*invp, cvt+p_lds write.
#define SCOMP_CALC(tt, pb)                                                         \
    {                                                                              \
        const char* kl = (const char*)&k_lds[(tt) % 3][0];                         \
        bf16x8 kf0 = *(const bf16x8*)(kl + (ch * 32 + lr) * 64 + lk * 16);         \
        bf16x8 kf1 = *(const bf16x8*)(kl + (ch * 32 + 16 + lr) * 64 + lk * 16);    \
        f32x4 s0 = mfma16(kf0, qf, (f32x4){0.f, 0.f, 0.f, 0.f});                   \
        f32x4 s1 = mfma16(kf1, qf, (f32x4){0.f, 0.f, 0.f, 0.f});                   \
        float e00 = __expf(s0[0]) * invp, e01 = __expf(s0[1]) * invp;              \
        float e02 = __expf(s0[2]) * invp, e03 = __expf(s0[3]) * invp;              \
        float e10 = __expf(s1[0]) * invp, e11 = __expf(s1[1]) * invp;              \
        float e12 = __expf(s1[2]) * invp, e13 = __expf(s1[3]) * invp;              \
        u32x2 pk0, pk1;                                                            \
        pk0[0] = cvt_pk_bf16(e00, e01); pk0[1] = cvt_pk_bf16(e02, e03);            \
        pk1[0] = cvt_pk_bf16(e10, e11); pk1[1] = cvt_pk_bf16(e12, e13);            \
        *(u32x2*)(&p_lds[pb][rg * 16 + lr][ch * 32 + lk * 4]) = pk0;               \
        *(u32x2*)(&p_lds[pb][rg * 16 + lr][ch * 32 + 16 + lk * 4]) = pk1;          \
    }

    // attention store for tile tt from p_lds[tt&1]: full-line nt stores.
#define ASTORE(tt)                                                                 \
    {                                                                              \
        const int arow = w * 8 + (l >> 3);                                         \
        const char* pr = (const char*)&p_lds[(tt) & 1][arow][0];                   \
        u32x2 u0 = *(const u32x2*)(pr + (l & 7) * 8);                              \
        u32x2 u1 = *(const u32x2*)(pr + 64 + (l & 7) * 8);                         \
        f32x4 f0, f1;                                                              \
        f0[0] = asf(u0[0] << 16); f0[1] = asf(u0[0] & 0xffff0000u);                \
        f0[2] = asf(u0[1] << 16); f0[3] = asf(u0[1] & 0xffff0000u);                \
        f1[0] = asf(u1[0] << 16); f1[1] = asf(u1[0] & 0xffff0000u);                \
        f1[2] = asf(u1[1] << 16); f1[3] = asf(u1[1] & 0xffff0000u);                \
        float* dst = attn_b + (size_t)(n0 + arow) * N_SZ + (tt) * 64 + (l & 7) * 4;\
        __builtin_nontemporal_store(f0, (f32x4*)dst);                              \
        __builtin_nontemporal_store(f1, (f32x4*)(dst + 32));                       \
    }

    // prologue
    STAGE(0, 0);
    STAGE(1, 1);
    __builtin_amdgcn_sched_barrier(0);
    asm volatile("s_waitcnt vmcnt(9)" ::: "memory");   // K(0) landed
    __builtin_amdgcn_sched_barrier(0);
    SCOMP_CALC(0, 0);

    for (int mt = 0; mt < 64; mt++) {
        asm volatile("s_waitcnt vmcnt(2) lgkmcnt(0)" ::: "memory");
        __builtin_amdgcn_sched_barrier(0);
        __builtin_amdgcn_s_barrier();
        __builtin_amdgcn_sched_barrier(0);
        const int cur = mt & 1;
        if (mt < 63) SCOMP_CALC(mt + 1, cur ^ 1);
        __builtin_amdgcn_sched_barrier(0);
        if (mt < 62) STAGE(mt + 2, (mt + 2) % 3);
        __builtin_amdgcn_sched_barrier(0);
        ASTORE(mt);
        __builtin_amdgcn_sched_barrier(0);
        // PV(mt): O[32 rows x 64 cols per wave] += P(32x64) @ v^T(64x64)
        const int vcur = mt % 3;
        const char* pbase = (const char*)&p_lds[cur][rp * 32 + lr][0];
        bf16x8 a00 = *(const bf16x8*)(pbase + lk * 16);
        bf16x8 a01 = *(const bf16x8*)(pbase + 64 + lk * 16);
        bf16x8 a10 = *(const bf16x8*)(pbase + 2304 + lk * 16);
        bf16x8 a11 = *(const bf16x8*)(pbase + 2304 + 64 + lk * 16);
        const char* vbase = (const char*)&v_lds[vcur][0];
#pragma unroll
        for (int cb = 0; cb < 4; cb++) {
            int c = cp * 64 + cb * 16 + lr;
            int sw = (c & 7) << 4;
            bf16x8 b0 = *(const bf16x8*)(vbase + c * 128 + ((lk << 4) ^ sw));
            bf16x8 b1 = *(const bf16x8*)(vbase + c * 128 + (((4 + lk) << 4) ^ sw));
            O[0][cb] = mfma16(a00, b0, O[0][cb]);
            O[0][cb] = mfma16(a01, b1, O[0][cb]);
            O[1][cb] = mfma16(a10, b0, O[1][cb]);
            O[1][cb] = mfma16(a11, b1, O[1][cb]);
        }
    }
#undef STAGE
#undef SCOMP_CALC
#undef ASTORE

    // ---- epilogue: out = gamma*O + x, transposed through LDS (reuse v_lds) ----
    __syncthreads();
    const float g = gamma_p[0];
    float* o_s = (float*)&v_lds[0][0];      // [32][258] f32 = 33 KB
    const float* xb = x + (size_t)b * C_SZ * N_SZ;
    float* ob = out + (size_t)b * C_SZ * N_SZ;
#pragma unroll
    for (int half = 0; half < 2; half++) {
        if (rp == half) {
#pragma unroll
            for (int rf = 0; rf < 2; rf++)
#pragma unroll
                for (int cb = 0; cb < 4; cb++)
#pragma unroll
                    for (int r = 0; r < 4; r++)
                        o_s[(rf * 16 + lk * 4 + r) * 258 + cp * 64 + cb * 16 + lr] = O[rf][cb][r];
        }
        __syncthreads();
        {
            int nn = t & 31;
            int c0 = t >> 5;   // 0..15
#pragma unroll
            for (int i = 0; i < 16; i++) {
                int c = c0 + 16 * i;
                size_t idx = (size_t)c * N_SZ + n0 + half * 32 + nn;
                ob[idx] = g * o_s[nn * 258 + c] + xb[idx];
            }
        }
        __syncthreads();
    }
}

extern "C" void kernel_launch(void* const* d_in, const int* in_sizes, int n_in,
                              void* d_out, int out_size, void* d_ws, size_t ws_size,
                              hipStream_t stream) {
    const float* x     = (const float*)d_in[0];
    const float* Wq    = (const float*)d_in[1];
    const float* bq    = (const float*)d_in[2];
    const float* Wk    = (const float*)d_in[3];
    const float* bk    = (const float*)d_in[4];
    const float* Wv    = (const float*)d_in[5];
    const float* bv    = (const float*)d_in[6];
    const float* gamma = (const float*)d_in[7];
    short* ws = (short*)d_ws;
    float* out = (float*)d_out;

    hipLaunchKernelGGL(k_convw, dim3(256), dim3(256), 0, stream, Wq, Wk, Wv, ws);
    hipLaunchKernelGGL(k_prep, dim3(256), dim3(256), 0, stream, x, bq, bk, bv, ws);
    hipLaunchKernelGGL(k_attn, dim3(256), dim3(512), 0, stream, ws, x, gamma, out);
}

// Round 6
// 137.400 us; speedup vs baseline: 1.2482x; 1.0335x over previous
//
#include <hip/hip_runtime.h>
#include <hip/hip_bf16.h>

typedef __attribute__((ext_vector_type(8))) short bf16x8;
typedef __attribute__((ext_vector_type(4))) float f32x4;
typedef __attribute__((ext_vector_type(4))) unsigned int u32x4;
typedef __attribute__((ext_vector_type(2))) unsigned int u32x2;

#define B_SZ 4
#define C_SZ 256
#define N_SZ 4096
#define DK_SZ 32

// ws layout in bf16 elements
#define WQB_OFF 0
#define WKB_OFF 8192
#define WVB_OFF 16384
#define QB_OFF  81920
#define KB_OFF  606208
#define VB_OFF  1130496

__device__ __forceinline__ short f2bf(float f) {
    union { float f; unsigned int u; } v; v.f = f;
    unsigned int r = v.u + 0x7fffu + ((v.u >> 16) & 1u);
    return (short)(r >> 16);
}

__device__ __forceinline__ unsigned int cvt_pk_bf16(float lo, float hi) {
    unsigned int r;
    asm volatile("v_cvt_pk_bf16_f32 %0, %1, %2" : "=v"(r) : "v"(lo), "v"(hi));
    return r;
}

__device__ __forceinline__ f32x4 mfma16(bf16x8 a, bf16x8 b, f32x4 c) {
    return __builtin_amdgcn_mfma_f32_16x16x32_bf16(a, b, c, 0, 0, 0);
}

__device__ __forceinline__ void gload_lds16(const void* g, void* l) {
    __builtin_amdgcn_global_load_lds((const __attribute__((address_space(1))) unsigned int*)g,
                                     (__attribute__((address_space(3))) unsigned int*)l, 16, 0, 0);
}

// XCD-affinity remap: grid = 256 1D, block i -> XCD i%8 (round-robin).
// Batch b owns XCDs {2b, 2b+1} -> per-XCD working set (V_b 2MB + K_b + Q_b) < 4MB L2.
__device__ __forceinline__ void remap_block(int i, int& b, int& n0) {
    b = (i & 7) >> 1;
    n0 = (((i >> 3) << 1) | (i & 1)) * 64;
}

// ---------------- weight conversion ----------------
__global__ __launch_bounds__(256) void k_convw(const float* __restrict__ Wq,
                                               const float* __restrict__ Wk,
                                               const float* __restrict__ Wv,
                                               short* __restrict__ ws) {
    int i = blockIdx.x * 256 + threadIdx.x;
    if (i < 8192) {
        ws[WQB_OFF + i] = f2bf(Wq[i]);
        ws[WKB_OFF + i] = f2bf(Wk[i]);
    }
    ws[WVB_OFF + i] = f2bf(Wv[i]);
}

// ---------------- projection: q, k as [b][n][32] bf16; v as [b][c][n] bf16 ----------------
__global__ __launch_bounds__(256) void k_prep(const float* __restrict__ x,
                                              const float* __restrict__ bq,
                                              const float* __restrict__ bk,
                                              const float* __restrict__ bv,
                                              short* __restrict__ ws) {
    __shared__ short xsT[64][264];
    __shared__ short vt_s[64][258];

    int b, n0;
    remap_block(blockIdx.x, b, n0);
    const int t = threadIdx.x;
    const float* xb = x + (size_t)b * C_SZ * N_SZ;

    {
        int c0 = t >> 4, n4 = (t & 15) * 4;
#pragma unroll
        for (int i = 0; i < 16; i++) {
            int c = c0 + 16 * i;
            float4 v = *(const float4*)(xb + (size_t)c * N_SZ + n0 + n4);
            xsT[n4 + 0][c] = f2bf(v.x);
            xsT[n4 + 1][c] = f2bf(v.y);
            xsT[n4 + 2][c] = f2bf(v.z);
            xsT[n4 + 3][c] = f2bf(v.w);
        }
    }
    __syncthreads();

    const int w = t >> 6, l = t & 63;
    const int lr = l & 15, lk = l >> 4;

    bf16x8 af[8];
#pragma unroll
    for (int kk = 0; kk < 8; kk++)
        af[kk] = *(const bf16x8*)(&xsT[w * 16 + lr][kk * 32 + lk * 8]);

#pragma unroll
    for (int qk = 0; qk < 2; qk++) {
        const short* wb = ws + (qk ? WKB_OFF : WQB_OFF);
        const float* bias = qk ? bk : bq;
        short* outp = ws + (qk ? KB_OFF : QB_OFF) + (size_t)b * N_SZ * DK_SZ;
#pragma unroll
        for (int cf = 0; cf < 2; cf++) {
            f32x4 acc = {0.f, 0.f, 0.f, 0.f};
#pragma unroll
            for (int kk = 0; kk < 8; kk++) {
                bf16x8 bfr = *(const bf16x8*)(wb + (cf * 16 + lr) * 256 + kk * 32 + lk * 8);
                acc = mfma16(af[kk], bfr, acc);
            }
            float bias_v = bias[cf * 16 + lr];
#pragma unroll
            for (int r = 0; r < 4; r++) {
                int row = w * 16 + lk * 4 + r;
                outp[(size_t)(n0 + row) * DK_SZ + cf * 16 + lr] = f2bf(acc[r] + bias_v);
            }
        }
    }

#pragma unroll
    for (int cf = 0; cf < 16; cf++) {
        f32x4 acc = {0.f, 0.f, 0.f, 0.f};
#pragma unroll
        for (int kk = 0; kk < 8; kk++) {
            bf16x8 bfr = *(const bf16x8*)(ws + WVB_OFF + (cf * 16 + lr) * 256 + kk * 32 + lk * 8);
            acc = mfma16(af[kk], bfr, acc);
        }
        float bias_v = bv[cf * 16 + lr];
#pragma unroll
        for (int r = 0; r < 4; r++) {
            vt_s[w * 16 + lk * 4 + r][cf * 16 + lr] = f2bf(acc[r] + bias_v);
        }
    }
    __syncthreads();
    {
        short* vb = ws + VB_OFF + (size_t)b * C_SZ * N_SZ;
        int nn = t & 63;
#pragma unroll
        for (int i = 0; i < 64; i++) {
            int c = (t >> 6) + 4 * i;
            vb[(size_t)c * N_SZ + n0 + nn] = vt_s[nn][c];
        }
    }
}

// ---------------- fused attention (wave-independent PV) ----------------
// 512 threads = 8 waves (rg = w&3: 16 q-rows; ch = w>>2: m-half of 32).
// Per iter: wait vmcnt(2)+lgkm(0); barrier; [A1+K ds issue] [STAGE(mt+2)]
// [SCOMP(mt+1): mfma, exp, nt stores, in-reg exchange -> pfN] [PV(mt): 16
// mfma, A2 reads]. P never touches LDS: swapped-QK^T output (m=4lk+r per
// lane) is permuted to PV B-frag layout (m=8lk+e) with 6 shfl_xor + selects.
// Each wave's PV computes O_partial[256c x 16n] over its m-half; ch-pairs
// reduced via LDS at the end. Only cross-wave coupling: V/K staging barrier.
__global__ __launch_bounds__(512, 1) void k_attn(const short* __restrict__ ws,
                                                 const float* __restrict__ x,
                                                 const float* __restrict__ gamma_p,
                                                 float* __restrict__ out) {
    __shared__ short v_lds[3][16384];   // V tiles [c][64] linear, slot^(c&7) swizzled; 96 KB
    __shared__ short k_lds[3][2304];    // K tiles [64][32] row-major, slot^((row>>1)&3) swizzled
    __shared__ float rsum_s[2][64];

    int b, n0;
    remap_block(blockIdx.x, b, n0);
    const int t = threadIdx.x, w = t >> 6, l = t & 63;
    const int rg = w & 3, ch = w >> 2;
    const int lr = l & 15, lk = l >> 4;

    const short* qb = ws + QB_OFF + (size_t)b * N_SZ * DK_SZ;
    const short* kb = ws + KB_OFF + (size_t)b * N_SZ * DK_SZ;
    const short* vb = ws + VB_OFF + (size_t)b * C_SZ * N_SZ;
    const char* kbb = (const char*)kb;

    bf16x8 qf = *(const bf16x8*)(qb + (size_t)(n0 + rg * 16 + lr) * DK_SZ + lk * 8);

    // ---- pass 1: rowsum of exp(S) over m-half ch, barrier-free ----
    float rs = 0.f;
    for (int mt = 0; mt < 32; mt++) {
        int mb = ch * 2048 + mt * 64;
        bf16x8 kfa = *(const bf16x8*)(kb + (size_t)(mb + lr) * DK_SZ + lk * 8);
        bf16x8 kfb = *(const bf16x8*)(kb + (size_t)(mb + 16 + lr) * DK_SZ + lk * 8);
        bf16x8 kfc = *(const bf16x8*)(kb + (size_t)(mb + 32 + lr) * DK_SZ + lk * 8);
        bf16x8 kfd = *(const bf16x8*)(kb + (size_t)(mb + 48 + lr) * DK_SZ + lk * 8);
        f32x4 s0 = mfma16(kfa, qf, (f32x4){0.f, 0.f, 0.f, 0.f});
        f32x4 s1 = mfma16(kfb, qf, (f32x4){0.f, 0.f, 0.f, 0.f});
        f32x4 s2 = mfma16(kfc, qf, (f32x4){0.f, 0.f, 0.f, 0.f});
        f32x4 s3 = mfma16(kfd, qf, (f32x4){0.f, 0.f, 0.f, 0.f});
#pragma unroll
        for (int r = 0; r < 4; r++)
            rs += __expf(s0[r]) + __expf(s1[r]) + __expf(s2[r]) + __expf(s3[r]);
    }
    rs += __shfl_xor(rs, 16);
    rs += __shfl_xor(rs, 32);
    if (l < 16) rsum_s[ch][rg * 16 + l] = rs;
    __syncthreads();
    const float invp = 1.f / (rsum_s[0][rg * 16 + lr] + rsum_s[1][rg * 16 + lr]);

    // ---- pass 2 ----
    float* attn_row = out + (size_t)B_SZ * C_SZ * N_SZ + (size_t)b * N_SZ * N_SZ
                      + (size_t)(n0 + rg * 16 + lr) * N_SZ;
    f32x4 O[16];
#pragma unroll
    for (int cb = 0; cb < 16; cb++) O[cb] = (f32x4){0.f, 0.f, 0.f, 0.f};

    const bool odd = lk & 1;
    const bool swp = ((lk >> 1) ^ (lk & 1)) & 1;
    const bool hi  = lk >> 1;
    const int krow = ch * 32 + lr;
    const int kswz = ((lk ^ ((lr >> 1) & 3)) << 4);
    const int voff = lr * 128 + ((((ch << 2) + lk) ^ (lr & 7)) << 4);

    bf16x8 kf0, kf1, pf, pfN;

#define STAGE(tt, buf)                                                              \
    {                                                                               \
        const int krw = w * 8 + (l >> 2);                                           \
        const int ksl = (l & 3) ^ ((l >> 3) & 3);                                   \
        gload_lds16(kbb + (size_t)(tt) * 4096 + krw * 64 + ksl * 16,                \
                    (void*)&k_lds[buf][w * 256]);                                   \
        const int mb = (tt) * 64;                                                   \
        _Pragma("unroll")                                                           \
        for (int i = 0; i < 4; i++) {                                               \
            int c = w * 32 + i * 8 + (l >> 3);                                      \
            int j = l & 7;                                                          \
            const short* gp = vb + (size_t)c * N_SZ + mb + ((j ^ (c & 7)) << 3);    \
            gload_lds16(gp, (void*)&v_lds[buf][(w * 32 + i * 8) * 64]);             \
        }                                                                           \
    }

#define KREAD(tt)                                                                   \
    {                                                                               \
        const char* kl = (const char*)&k_lds[(tt) % 3][0];                          \
        kf0 = *(const bf16x8*)(kl + krow * 64 + kswz);                              \
        kf1 = *(const bf16x8*)(kl + krow * 64 + 1024 + kswz);                       \
    }

    // SCOMP(tt): S = mfma(K,Q); e = exp*inv; nt stores; exchange -> pfN.
    // Exchange (verified): step1 xor-16 keeps pk[lk&1], receives partner's;
    // step2 conditional xor-48 (groups 1,2 swap); assemble by hi = lk>>1.
#define SCOMP_BODY(tt)                                                              \
    {                                                                               \
        f32x4 s0 = mfma16(kf0, qf, (f32x4){0.f, 0.f, 0.f, 0.f});                    \
        f32x4 s1 = mfma16(kf1, qf, (f32x4){0.f, 0.f, 0.f, 0.f});                    \
        f32x4 ev0, ev1;                                                             \
        ev0[0] = __expf(s0[0]) * invp; ev0[1] = __expf(s0[1]) * invp;               \
        ev0[2] = __expf(s0[2]) * invp; ev0[3] = __expf(s0[3]) * invp;               \
        ev1[0] = __expf(s1[0]) * invp; ev1[1] = __expf(s1[1]) * invp;               \
        ev1[2] = __expf(s1[2]) * invp; ev1[3] = __expf(s1[3]) * invp;               \
        const int mbase = (tt) * 64 + ch * 32 + 4 * lk;                             \
        __builtin_nontemporal_store(ev0, (f32x4*)(attn_row + mbase));               \
        __builtin_nontemporal_store(ev1, (f32x4*)(attn_row + mbase + 16));          \
        unsigned pkA0 = cvt_pk_bf16(ev0[0], ev0[1]);                                \
        unsigned pkA1 = cvt_pk_bf16(ev0[2], ev0[3]);                                \
        unsigned pkB0 = cvt_pk_bf16(ev1[0], ev1[1]);                                \
        unsigned pkB1 = cvt_pk_bf16(ev1[2], ev1[3]);                                \
        unsigned sw0 = odd ? pkA0 : pkB0;                                           \
        unsigned sw1 = odd ? pkA1 : pkB1;                                           \
        unsigned R0 = __shfl_xor(sw0, 16);                                          \
        unsigned R1 = __shfl_xor(sw1, 16);                                          \
        unsigned Kp0 = odd ? pkB0 : pkA0;                                           \
        unsigned Kp1 = odd ? pkB1 : pkA1;                                           \
        unsigned x0 = __shfl_xor(Kp0, 48); Kp0 = swp ? x0 : Kp0;                    \
        unsigned x1 = __shfl_xor(Kp1, 48); Kp1 = swp ? x1 : Kp1;                    \
        unsigned x2 = __shfl_xor(R0, 48);  R0  = swp ? x2 : R0;                     \
        unsigned x3 = __shfl_xor(R1, 48);  R1  = swp ? x3 : R1;                     \
        u32x4 pw;                                                                   \
        pw[0] = hi ? R0 : Kp0; pw[1] = hi ? R1 : Kp1;                               \
        pw[2] = hi ? Kp0 : R0; pw[3] = hi ? Kp1 : R1;                               \
        pfN = __builtin_bit_cast(bf16x8, pw);                                       \
    }

    // prologue
    STAGE(0, 0);
    STAGE(1, 1);
    __builtin_amdgcn_sched_barrier(0);
    asm volatile("s_waitcnt vmcnt(5)" ::: "memory");   // stage(0) landed
    __builtin_amdgcn_sched_barrier(0);
    __builtin_amdgcn_s_barrier();
    KREAD(0);
    SCOMP_BODY(0);
    pf = pfN;

    for (int mt = 0; mt < 64; mt++) {
        asm volatile("s_waitcnt vmcnt(2) lgkmcnt(0)" ::: "memory");
        __builtin_amdgcn_sched_barrier(0);
        __builtin_amdgcn_s_barrier();
        __builtin_amdgcn_sched_barrier(0);
        // A1 + K issue
        const char* vbase = (const char*)&v_lds[mt % 3][0];
        if (mt < 63) KREAD(mt + 1);
        bf16x8 A1[8];
#pragma unroll
        for (int cb = 0; cb < 8; cb++)
            A1[cb] = *(const bf16x8*)(vbase + cb * 2048 + voff);
        // stage next-next tile (before the stores, for vmcnt order)
        if (mt < 62) STAGE(mt + 2, (mt + 2) % 3);
        __builtin_amdgcn_sched_barrier(0);
        if (mt < 63) SCOMP_BODY(mt + 1);
        __builtin_amdgcn_sched_barrier(0);
        // PV(mt): O_partial[256c x 16n] += V_half^T-frags * pf
        bf16x8 A2[8];
#pragma unroll
        for (int cb = 0; cb < 8; cb++)
            A2[cb] = *(const bf16x8*)(vbase + (cb + 8) * 2048 + voff);
#pragma unroll
        for (int cb = 0; cb < 8; cb++) O[cb] = mfma16(A1[cb], pf, O[cb]);
#pragma unroll
        for (int cb = 0; cb < 8; cb++) O[cb + 8] = mfma16(A2[cb], pf, O[cb + 8]);
        pf = pfN;
    }
#undef STAGE
#undef KREAD
#undef SCOMP_BODY

    // ---- epilogue: reduce ch-pairs through LDS, then out = gamma*O + x ----
    __syncthreads();
    float* o_red = (float*)&v_lds[0][0];     // [4 rg][256 c][16 n], stride 17, rg-stride 4360
    const int RSTRIDE = 4360;
    if (ch == 1) {
#pragma unroll
        for (int cb = 0; cb < 16; cb++)
#pragma unroll
            for (int r = 0; r < 4; r++)
                o_red[rg * RSTRIDE + (cb * 16 + 4 * lk + r) * 17 + lr] = O[cb][r];
    }
    __syncthreads();
    if (ch == 0) {
#pragma unroll
        for (int cb = 0; cb < 16; cb++)
#pragma unroll
            for (int r = 0; r < 4; r++) {
                int idx = rg * RSTRIDE + (cb * 16 + 4 * lk + r) * 17 + lr;
                o_red[idx] += O[cb][r];
            }
    }
    __syncthreads();
    {
        const float g = gamma_p[0];
        const float* xb = x + (size_t)b * C_SZ * N_SZ;
        float* ob = out + (size_t)b * C_SZ * N_SZ;
        int nn = t & 63;
        int c0 = t >> 6;   // 0..7
        int rbase = (nn >> 4) * RSTRIDE + (nn & 15);
#pragma unroll
        for (int i = 0; i < 32; i++) {
            int c = c0 + 8 * i;
            size_t idx = (size_t)c * N_SZ + n0 + nn;
            ob[idx] = g * o_red[rbase + c * 17] + xb[idx];
        }
    }
}

extern "C" void kernel_launch(void* const* d_in, const int* in_sizes, int n_in,
                              void* d_out, int out_size, void* d_ws, size_t ws_size,
                              hipStream_t stream) {
    const float* x     = (const float*)d_in[0];
    const float* Wq    = (const float*)d_in[1];
    const float* bq    = (const float*)d_in[2];
    const float* Wk    = (const float*)d_in[3];
    const float* bk    = (const float*)d_in[4];
    const float* Wv    = (const float*)d_in[5];
    const float* bv    = (const float*)d_in[6];
    const float* gamma = (const float*)d_in[7];
    short* ws = (short*)d_ws;
    float* out = (float*)d_out;

    hipLaunchKernelGGL(k_convw, dim3(256), dim3(256), 0, stream, Wq, Wk, Wv, ws);
    hipLaunchKernelGGL(k_prep, dim3(256), dim3(256), 0, stream, x, bq, bk, bv, ws);
    hipLaunchKernelGGL(k_attn, dim3(256), dim3(512), 0, stream, ws, x, gamma, out);
}

// Round 7
// 137.314 us; speedup vs baseline: 1.2490x; 1.0006x over previous
//
#include <hip/hip_runtime.h>
#include <hip/hip_bf16.h>

typedef __attribute__((ext_vector_type(8))) short bf16x8;
typedef __attribute__((ext_vector_type(4))) float f32x4;
typedef __attribute__((ext_vector_type(4))) unsigned int u32x4;
typedef __attribute__((ext_vector_type(2))) unsigned int u32x2;

#define B_SZ 4
#define C_SZ 256
#define N_SZ 4096
#define DK_SZ 32

// ws layout in bf16 elements
#define WQB_OFF 0
#define WKB_OFF 8192
#define WVB_OFF 16384
#define QB_OFF  81920
#define KB_OFF  606208
#define VB_OFF  1130496

__device__ __forceinline__ short f2bf(float f) {
    union { float f; unsigned int u; } v; v.f = f;
    unsigned int r = v.u + 0x7fffu + ((v.u >> 16) & 1u);
    return (short)(r >> 16);
}

__device__ __forceinline__ unsigned int cvt_pk_bf16(float lo, float hi) {
    unsigned int r;
    asm volatile("v_cvt_pk_bf16_f32 %0, %1, %2" : "=v"(r) : "v"(lo), "v"(hi));
    return r;
}

__device__ __forceinline__ f32x4 mfma16(bf16x8 a, bf16x8 b, f32x4 c) {
    return __builtin_amdgcn_mfma_f32_16x16x32_bf16(a, b, c, 0, 0, 0);
}

__device__ __forceinline__ void gload_lds16(const void* g, void* l) {
    __builtin_amdgcn_global_load_lds((const __attribute__((address_space(1))) unsigned int*)g,
                                     (__attribute__((address_space(3))) unsigned int*)l, 16, 0, 0);
}

// XCD-affinity remap: grid = 256 1D, block i -> XCD i%8 (round-robin).
// Batch b owns XCDs {2b, 2b+1} -> per-XCD working set (V_b 2MB + K_b + Q_b) < 4MB L2.
__device__ __forceinline__ void remap_block(int i, int& b, int& n0) {
    b = (i & 7) >> 1;
    n0 = (((i >> 3) << 1) | (i & 1)) * 64;
}

// ---------------- weight conversion ----------------
__global__ __launch_bounds__(256) void k_convw(const float* __restrict__ Wq,
                                               const float* __restrict__ Wk,
                                               const float* __restrict__ Wv,
                                               short* __restrict__ ws) {
    int i = blockIdx.x * 256 + threadIdx.x;
    if (i < 8192) {
        ws[WQB_OFF + i] = f2bf(Wq[i]);
        ws[WKB_OFF + i] = f2bf(Wk[i]);
    }
    ws[WVB_OFF + i] = f2bf(Wv[i]);
}

// ---------------- projection: q, k as [b][n][32] bf16; v as [b][c][n] bf16 ----------------
__global__ __launch_bounds__(256) void k_prep(const float* __restrict__ x,
                                              const float* __restrict__ bq,
                                              const float* __restrict__ bk,
                                              const float* __restrict__ bv,
                                              short* __restrict__ ws) {
    __shared__ short xsT[64][264];
    __shared__ short vt_s[64][258];

    int b, n0;
    remap_block(blockIdx.x, b, n0);
    const int t = threadIdx.x;
    const float* xb = x + (size_t)b * C_SZ * N_SZ;

    {
        int c0 = t >> 4, n4 = (t & 15) * 4;
#pragma unroll
        for (int i = 0; i < 16; i++) {
            int c = c0 + 16 * i;
            float4 v = *(const float4*)(xb + (size_t)c * N_SZ + n0 + n4);
            xsT[n4 + 0][c] = f2bf(v.x);
            xsT[n4 + 1][c] = f2bf(v.y);
            xsT[n4 + 2][c] = f2bf(v.z);
            xsT[n4 + 3][c] = f2bf(v.w);
        }
    }
    __syncthreads();

    const int w = t >> 6, l = t & 63;
    const int lr = l & 15, lk = l >> 4;

    bf16x8 af[8];
#pragma unroll
    for (int kk = 0; kk < 8; kk++)
        af[kk] = *(const bf16x8*)(&xsT[w * 16 + lr][kk * 32 + lk * 8]);

#pragma unroll
    for (int qk = 0; qk < 2; qk++) {
        const short* wb = ws + (qk ? WKB_OFF : WQB_OFF);
        const float* bias = qk ? bk : bq;
        short* outp = ws + (qk ? KB_OFF : QB_OFF) + (size_t)b * N_SZ * DK_SZ;
#pragma unroll
        for (int cf = 0; cf < 2; cf++) {
            f32x4 acc = {0.f, 0.f, 0.f, 0.f};
#pragma unroll
            for (int kk = 0; kk < 8; kk++) {
                bf16x8 bfr = *(const bf16x8*)(wb + (cf * 16 + lr) * 256 + kk * 32 + lk * 8);
                acc = mfma16(af[kk], bfr, acc);
            }
            float bias_v = bias[cf * 16 + lr];
#pragma unroll
            for (int r = 0; r < 4; r++) {
                int row = w * 16 + lk * 4 + r;
                outp[(size_t)(n0 + row) * DK_SZ + cf * 16 + lr] = f2bf(acc[r] + bias_v);
            }
        }
    }

#pragma unroll
    for (int cf = 0; cf < 16; cf++) {
        f32x4 acc = {0.f, 0.f, 0.f, 0.f};
#pragma unroll
        for (int kk = 0; kk < 8; kk++) {
            bf16x8 bfr = *(const bf16x8*)(ws + WVB_OFF + (cf * 16 + lr) * 256 + kk * 32 + lk * 8);
            acc = mfma16(af[kk], bfr, acc);
        }
        float bias_v = bv[cf * 16 + lr];
#pragma unroll
        for (int r = 0; r < 4; r++) {
            vt_s[w * 16 + lk * 4 + r][cf * 16 + lr] = f2bf(acc[r] + bias_v);
        }
    }
    __syncthreads();
    {
        short* vb = ws + VB_OFF + (size_t)b * C_SZ * N_SZ;
        int nn = t & 63;
#pragma unroll
        for (int i = 0; i < 64; i++) {
            int c = (t >> 6) + 4 * i;
            vb[(size_t)c * N_SZ + n0 + nn] = vt_s[nn][c];
        }
    }
}

// ---------------- fused attention (minimal-duplication PV) ----------------
// 512 threads = 8 waves. SCOMP mapping: rg=w&3 (16 q-rows), ch=w>>2 (m-half).
// PV mapping:    cq=w&3 (64-channel quarter), mh=w>>2 (m-half) -> each V
// element read by exactly ONE wave (4 b128/wave vs 16 before). P goes through
// a small double-buffered LDS tile (8 KB): SCOMP writes its 16n x 32m slice,
// PV reads 4 B-frags covering all 64 n for its m-half. O partials (per m-half)
// reduced across mh-pairs in the epilogue.
// Per iter (1 barrier): wait vmcnt(2)+lgkm(0); barrier; KREAD(t+1);
// STAGE(t+2); SCOMP(t+1) [mfma, exp, nt stores, P->p_lds[alt]]; PV(t).
// Stores are the 2 newest vm ops -> vmcnt(2) never waits on a store ack.
__global__ __launch_bounds__(512, 1) void k_attn(const short* __restrict__ ws,
                                                 const float* __restrict__ x,
                                                 const float* __restrict__ gamma_p,
                                                 float* __restrict__ out) {
    __shared__ short v_lds[3][16384];   // V tiles [c][64] linear, slot^(c&7) swizzled; 96 KB
    __shared__ short k_lds[3][2304];    // K tiles [64][32], slot^((row>>1)&3) swizzled
    __shared__ short p_lds[2][64][72];  // P tiles [n][m], stride 144 B; 18.4 KB
    __shared__ float rsum_s[2][64];

    int b, n0;
    remap_block(blockIdx.x, b, n0);
    const int t = threadIdx.x, w = t >> 6, l = t & 63;
    const int rg = w & 3, ch = w >> 2;   // rg=cq for PV, ch=mh
    const int lr = l & 15, lk = l >> 4;

    const short* qb = ws + QB_OFF + (size_t)b * N_SZ * DK_SZ;
    const short* kb = ws + KB_OFF + (size_t)b * N_SZ * DK_SZ;
    const short* vb = ws + VB_OFF + (size_t)b * C_SZ * N_SZ;
    const char* kbb = (const char*)kb;

    bf16x8 qf = *(const bf16x8*)(qb + (size_t)(n0 + rg * 16 + lr) * DK_SZ + lk * 8);

    // ---- pass 1: rowsum of exp(S) over m-half ch, barrier-free ----
    float rs = 0.f;
    for (int mt = 0; mt < 32; mt++) {
        int mb = ch * 2048 + mt * 64;
        bf16x8 kfa = *(const bf16x8*)(kb + (size_t)(mb + lr) * DK_SZ + lk * 8);
        bf16x8 kfb = *(const bf16x8*)(kb + (size_t)(mb + 16 + lr) * DK_SZ + lk * 8);
        bf16x8 kfc = *(const bf16x8*)(kb + (size_t)(mb + 32 + lr) * DK_SZ + lk * 8);
        bf16x8 kfd = *(const bf16x8*)(kb + (size_t)(mb + 48 + lr) * DK_SZ + lk * 8);
        f32x4 s0 = mfma16(kfa, qf, (f32x4){0.f, 0.f, 0.f, 0.f});
        f32x4 s1 = mfma16(kfb, qf, (f32x4){0.f, 0.f, 0.f, 0.f});
        f32x4 s2 = mfma16(kfc, qf, (f32x4){0.f, 0.f, 0.f, 0.f});
        f32x4 s3 = mfma16(kfd, qf, (f32x4){0.f, 0.f, 0.f, 0.f});
#pragma unroll
        for (int r = 0; r < 4; r++)
            rs += __expf(s0[r]) + __expf(s1[r]) + __expf(s2[r]) + __expf(s3[r]);
    }
    rs += __shfl_xor(rs, 16);
    rs += __shfl_xor(rs, 32);
    if (l < 16) rsum_s[ch][rg * 16 + l] = rs;
    __syncthreads();
    const float invp = 1.f / (rsum_s[0][rg * 16 + lr] + rsum_s[1][rg * 16 + lr]);

    // ---- pass 2 ----
    float* attn_row = out + (size_t)B_SZ * C_SZ * N_SZ + (size_t)b * N_SZ * N_SZ
                      + (size_t)(n0 + rg * 16 + lr) * N_SZ;
    f32x4 O[4][4];   // O[cf][rgi]: c = rg*64+cf*16+4lk+r, n = rgi*16+lr (m-half partial)
#pragma unroll
    for (int cf = 0; cf < 4; cf++)
#pragma unroll
        for (int rgi = 0; rgi < 4; rgi++) O[cf][rgi] = (f32x4){0.f, 0.f, 0.f, 0.f};

    const int krow = ch * 32 + lr;
    const int kswz = ((lk ^ ((lr >> 1) & 3)) << 4);
    // PV A-frag offset within v_lds tile: c = rg*64 + cf*16 + lr, m-chunk = ch*4+lk
    const int aoff = rg * 8192 + lr * 128 + ((((ch << 2) + lk) ^ (lr & 7)) << 4);
    // PV B-frag byte offset within p_lds tile: row rgi*16+lr, m = ch*32+lk*8
    const int boff = lr * 144 + ch * 64 + lk * 16;

    bf16x8 kf0, kf1;

#define STAGE(tt, buf)                                                              \
    {                                                                               \
        const int krw = w * 8 + (l >> 2);                                           \
        const int ksl = (l & 3) ^ ((l >> 3) & 3);                                   \
        gload_lds16(kbb + (size_t)(tt) * 4096 + krw * 64 + ksl * 16,                \
                    (void*)&k_lds[buf][w * 256]);                                   \
        const int mb = (tt) * 64;                                                   \
        _Pragma("unroll")                                                           \
        for (int i = 0; i < 4; i++) {                                               \
            int c = w * 32 + i * 8 + (l >> 3);                                      \
            int j = l & 7;                                                          \
            const short* gp = vb + (size_t)c * N_SZ + mb + ((j ^ (c & 7)) << 3);    \
            gload_lds16(gp, (void*)&v_lds[buf][(w * 32 + i * 8) * 64]);             \
        }                                                                           \
    }

#define KREAD(tt)                                                                   \
    {                                                                               \
        const char* kl = (const char*)&k_lds[(tt) % 3][0];                          \
        kf0 = *(const bf16x8*)(kl + krow * 64 + kswz);                              \
        kf1 = *(const bf16x8*)(kl + krow * 64 + 1024 + kswz);                       \
    }

    // SCOMP(tt): S = mfma(K,Q); e = exp*inv; nt stores; P -> p_lds[pb].
#define SCOMP_BODY(tt, pb)                                                          \
    {                                                                               \
        f32x4 s0 = mfma16(kf0, qf, (f32x4){0.f, 0.f, 0.f, 0.f});                    \
        f32x4 s1 = mfma16(kf1, qf, (f32x4){0.f, 0.f, 0.f, 0.f});                    \
        f32x4 ev0, ev1;                                                             \
        ev0[0] = __expf(s0[0]) * invp; ev0[1] = __expf(s0[1]) * invp;               \
        ev0[2] = __expf(s0[2]) * invp; ev0[3] = __expf(s0[3]) * invp;               \
        ev1[0] = __expf(s1[0]) * invp; ev1[1] = __expf(s1[1]) * invp;               \
        ev1[2] = __expf(s1[2]) * invp; ev1[3] = __expf(s1[3]) * invp;               \
        const int mbase = (tt) * 64 + ch * 32 + 4 * lk;                             \
        __builtin_nontemporal_store(ev0, (f32x4*)(attn_row + mbase));               \
        __builtin_nontemporal_store(ev1, (f32x4*)(attn_row + mbase + 16));          \
        u32x2 pk0, pk1;                                                             \
        pk0[0] = cvt_pk_bf16(ev0[0], ev0[1]); pk0[1] = cvt_pk_bf16(ev0[2], ev0[3]); \
        pk1[0] = cvt_pk_bf16(ev1[0], ev1[1]); pk1[1] = cvt_pk_bf16(ev1[2], ev1[3]); \
        *(u32x2*)(&p_lds[pb][rg * 16 + lr][ch * 32 + lk * 4]) = pk0;                \
        *(u32x2*)(&p_lds[pb][rg * 16 + lr][ch * 32 + 16 + lk * 4]) = pk1;           \
    }

    // prologue
    STAGE(0, 0);
    STAGE(1, 1);
    __builtin_amdgcn_sched_barrier(0);
    asm volatile("s_waitcnt vmcnt(5)" ::: "memory");   // stage(0) landed
    __builtin_amdgcn_sched_barrier(0);
    __builtin_amdgcn_s_barrier();
    KREAD(0);
    SCOMP_BODY(0, 0);

    for (int mt = 0; mt < 64; mt++) {
        asm volatile("s_waitcnt vmcnt(2) lgkmcnt(0)" ::: "memory");
        __builtin_amdgcn_sched_barrier(0);
        __builtin_amdgcn_s_barrier();
        __builtin_amdgcn_sched_barrier(0);
        const int cur = mt & 1;
        if (mt < 63) KREAD(mt + 1);
        if (mt < 62) STAGE(mt + 2, (mt + 2) % 3);
        __builtin_amdgcn_sched_barrier(0);
        if (mt < 63) SCOMP_BODY(mt + 1, cur ^ 1);
        __builtin_amdgcn_sched_barrier(0);
        // PV(mt): O[c = cq-quarter][n = all 64] += V-frags(1x read) * P-frags
        const char* vbase = (const char*)&v_lds[mt % 3][0];
        const char* pbase = (const char*)&p_lds[cur][0][0];
        bf16x8 Afr[4], Bfr[4];
#pragma unroll
        for (int cf = 0; cf < 4; cf++)
            Afr[cf] = *(const bf16x8*)(vbase + cf * 2048 + aoff);
#pragma unroll
        for (int rgi = 0; rgi < 4; rgi++)
            Bfr[rgi] = *(const bf16x8*)(pbase + rgi * 2304 + boff);
#pragma unroll
        for (int cf = 0; cf < 4; cf++)
#pragma unroll
            for (int rgi = 0; rgi < 4; rgi++)
                O[cf][rgi] = mfma16(Afr[cf], Bfr[rgi], O[cf][rgi]);
    }
#undef STAGE
#undef KREAD
#undef SCOMP_BODY

    // ---- epilogue: reduce mh-pairs through LDS, then out = gamma*O + x ----
    __syncthreads();
    float* o_red = (float*)&v_lds[0][0];     // [4 n-grp][256 c][16 n], c-stride 17
    const int RSTRIDE = 4360;
    if (ch == 1) {
#pragma unroll
        for (int cf = 0; cf < 4; cf++)
#pragma unroll
            for (int rgi = 0; rgi < 4; rgi++)
#pragma unroll
                for (int r = 0; r < 4; r++)
                    o_red[rgi * RSTRIDE + (rg * 64 + cf * 16 + 4 * lk + r) * 17 + lr] = O[cf][rgi][r];
    }
    __syncthreads();
    if (ch == 0) {
#pragma unroll
        for (int cf = 0; cf < 4; cf++)
#pragma unroll
            for (int rgi = 0; rgi < 4; rgi++)
#pragma unroll
                for (int r = 0; r < 4; r++) {
                    int idx = rgi * RSTRIDE + (rg * 64 + cf * 16 + 4 * lk + r) * 17 + lr;
                    o_red[idx] += O[cf][rgi][r];
                }
    }
    __syncthreads();
    {
        const float g = gamma_p[0];
        const float* xb = x + (size_t)b * C_SZ * N_SZ;
        float* ob = out + (size_t)b * C_SZ * N_SZ;
        int nn = t & 63;
        int c0 = t >> 6;   // 0..7
        int rbase = (nn >> 4) * RSTRIDE + (nn & 15);
#pragma unroll
        for (int i = 0; i < 32; i++) {
            int c = c0 + 8 * i;
            size_t idx = (size_t)c * N_SZ + n0 + nn;
            ob[idx] = g * o_red[rbase + c * 17] + xb[idx];
        }
    }
}

extern "C" void kernel_launch(void* const* d_in, const int* in_sizes, int n_in,
                              void* d_out, int out_size, void* d_ws, size_t ws_size,
                              hipStream_t stream) {
    const float* x     = (const float*)d_in[0];
    const float* Wq    = (const float*)d_in[1];
    const float* bq    = (const float*)d_in[2];
    const float* Wk    = (const float*)d_in[3];
    const float* bk    = (const float*)d_in[4];
    const float* Wv    = (const float*)d_in[5];
    const float* bv    = (const float*)d_in[6];
    const float* gamma = (const float*)d_in[7];
    short* ws = (short*)d_ws;
    float* out = (float*)d_out;

    hipLaunchKernelGGL(k_convw, dim3(256), dim3(256), 0, stream, Wq, Wk, Wv, ws);
    hipLaunchKernelGGL(k_prep, dim3(256), dim3(256), 0, stream, x, bq, bk, bv, ws);
    hipLaunchKernelGGL(k_attn, dim3(256), dim3(512), 0, stream, ws, x, gamma, out);
}